// Round 8
// baseline (247.150 us; speedup 1.0000x reference)
//
#include <hip/hip_runtime.h>

// BERT joint NER+relation head on MI355X (gfx950).
// Inputs: fp32. Output: fp32 flat [tags(1024) | scores(3145728)].
// R8: scorer tanh -> clamped Pade(3,2) (1 rcp, no exp; trans-pipe bound fix);
// prep merged into GEMM kernel; Viterbi standalone with lane<9 store guard.

typedef unsigned short ushort_t;
typedef __attribute__((ext_vector_type(8))) short bf16x8;
typedef __attribute__((ext_vector_type(4))) float f32x4;
typedef __attribute__((ext_vector_type(4))) int i32x4;

// workspace offsets (bytes), all 16-aligned; total 3,400,960 B
#define WS_UW2   0u         // ushort [1024][1600] : bf16( embed@[U|W] + bias )
#define WS_NER   3276800u   // float  [1024][9]
#define WS_VFRAG 3313664u   // ushort [25][64][8]  : V as 16x16x32 B-fragments (bf16)
#define WS_LAB2  3339264u   // float  [9][1600]    : label_emb@[U|W][768:]
#define WS_TAGS  3396864u   // int    [1024]

__device__ __forceinline__ unsigned f2b(float f){          // RNE, finite only
  unsigned u = __float_as_uint(f);
  return (u + 0x7FFFu + ((u>>16)&1u)) >> 16;
}
// bf16 pair via v_perm_b32 (truncation): bits[15:0]=bf16(lo), bits[31:16]=bf16(hi)
__device__ __forceinline__ unsigned pkbf16(float hi, float lo){
  return __builtin_amdgcn_perm(__float_as_uint(hi), __float_as_uint(lo), 0x07060302u);
}
__device__ __forceinline__ float lo16(int v){ return __uint_as_float(((unsigned)v)<<16); }
__device__ __forceinline__ float hi16(int v){ return __uint_as_float(((unsigned)v)&0xFFFF0000u); }
// hi half as fp32 WITHOUT masking low garbage bits (err < 2^-8 rel, ~bf16 noise)
__device__ __forceinline__ float hi16g(int v){ return __uint_as_float((unsigned)v); }
// clamped Pade(3,2): tanh(x) ~= x(27+x^2)/(27+9x^2) on |x|<=3.9, max err ~0.024
__device__ __forceinline__ float tanh_pade(float x){
  x = fminf(fmaxf(x, -3.9f), 3.9f);
  float t = x*x;
  float n = x*(t + 27.0f);
  float d = __builtin_fmaf(t, 9.0f, 27.0f);
  return n * __builtin_amdgcn_rcpf(d);
}

// ---------------------------------------- K1: GEMM + prep (763 blocks) ----
// blocks [0,400): GEMM; [400,450): V frags; [450,706): ner; [706,763): lab2
__global__ __launch_bounds__(256) void gemm_prep_kernel(
    const float* __restrict__ embed, const float* __restrict__ lw,
    const float* __restrict__ lb,    const float* __restrict__ lemb,
    const float* __restrict__ uw,    const float* __restrict__ ub,
    const float* __restrict__ ww,    const float* __restrict__ wb,
    const float* __restrict__ vw,    char* __restrict__ ws)
{
  __shared__ char smem[10496];
  int bx = blockIdx.x, tid = threadIdx.x;
  if (bx < 400) {
    // uw2[1024][1600] = bf16( embed[1024,768] @ [U_w|W_w][768,1600] + bias )
    ushort_t (*As)[40] = (ushort_t(*)[40])smem;            // [m][k] +8 pad, 5120 B
    ushort_t (*Bs)[42] = (ushort_t(*)[42])(smem + 5120);   // [n][k] +10 pad, 5376 B
    ushort_t* uw2 = (ushort_t*)(ws + WS_UW2);
    int bm = bx & 15, bn = bx >> 4;
    int M0 = bm*64, N0 = bn*64;
    int w = tid>>6, lane = tid&63;
    int wr = w>>1, wc = w&1;
    int m16 = lane&15, quad = lane>>4;
    int nl = tid>>2, k8 = (tid&3)<<3;
    int bnn = tid & 63, bw = tid >> 6;
    int gn = N0 + bnn;
    const float* bsrc = uw; int bcol = 0; bool bzero = true;
    if (gn < 798)                    { bsrc = uw; bcol = gn;     bzero = false; }
    else if (gn >= 800 && gn < 1598) { bsrc = ww; bcol = gn-800; bzero = false; }

    f32x4 acc[2][2];
    #pragma unroll
    for (int mi=0;mi<2;mi++)
      #pragma unroll
      for (int ni=0;ni<2;ni++) acc[mi][ni] = (f32x4){0.f,0.f,0.f,0.f};

    f32x4 a_lo, a_hi; float bvals[8];
    {
      const float* ap = &embed[(M0+nl)*768 + k8];
      a_lo = *(const f32x4*)ap; a_hi = *(const f32x4*)(ap+4);
      #pragma unroll
      for (int r=0;r<4;r++) {
        int kk = r*8 + bw*2;
        bvals[2*r]   = bzero ? 0.f : bsrc[(kk  )*798 + bcol];
        bvals[2*r+1] = bzero ? 0.f : bsrc[(kk+1)*798 + bcol];
      }
    }
    for (int k0=0; k0<768; k0+=32) {
      i32x4 av = (i32x4){ (int)pkbf16(a_lo.y,a_lo.x), (int)pkbf16(a_lo.w,a_lo.z),
                          (int)pkbf16(a_hi.y,a_hi.x), (int)pkbf16(a_hi.w,a_hi.z) };
      *(i32x4*)&As[nl][k8] = av;
      #pragma unroll
      for (int r=0;r<4;r++) {
        int kk = r*8 + bw*2;
        *(unsigned*)&Bs[bnn][kk] = pkbf16(bvals[2*r+1], bvals[2*r]);
      }
      __syncthreads();
      if (k0 + 32 < 768) {
        const float* ap = &embed[(M0+nl)*768 + k0 + 32 + k8];
        a_lo = *(const f32x4*)ap; a_hi = *(const f32x4*)(ap+4);
        #pragma unroll
        for (int r=0;r<4;r++) {
          int kk = r*8 + bw*2;
          bvals[2*r]   = bzero ? 0.f : bsrc[(k0+32+kk  )*798 + bcol];
          bvals[2*r+1] = bzero ? 0.f : bsrc[(k0+32+kk+1)*798 + bcol];
        }
      }
      bf16x8 a0 = *(const bf16x8*)&As[wr*32      + m16][quad*8];
      bf16x8 a1 = *(const bf16x8*)&As[wr*32 + 16 + m16][quad*8];
      bf16x8 b0 = *(const bf16x8*)&Bs[wc*32      + m16][quad*8];
      bf16x8 b1 = *(const bf16x8*)&Bs[wc*32 + 16 + m16][quad*8];
      acc[0][0] = __builtin_amdgcn_mfma_f32_16x16x32_bf16(a0,b0,acc[0][0],0,0,0);
      acc[0][1] = __builtin_amdgcn_mfma_f32_16x16x32_bf16(a0,b1,acc[0][1],0,0,0);
      acc[1][0] = __builtin_amdgcn_mfma_f32_16x16x32_bf16(a1,b0,acc[1][0],0,0,0);
      acc[1][1] = __builtin_amdgcn_mfma_f32_16x16x32_bf16(a1,b1,acc[1][1],0,0,0);
      __syncthreads();
    }
    #pragma unroll
    for (int mi=0;mi<2;mi++)
      #pragma unroll
      for (int ni=0;ni<2;ni++)
        #pragma unroll
        for (int reg=0;reg<4;reg++) {
          int gm = M0 + wr*32 + mi*16 + quad*4 + reg;
          int go = N0 + wc*32 + ni*16 + m16;
          float bias = 0.f;
          if (go < 798) bias = ub[go];
          else if (go >= 800 && go < 1598) bias = wb[go-800];
          float v = acc[mi][ni][reg] + bias;
          uw2[gm*1600 + go] = (ushort_t)f2b(v);
        }
  } else if (bx < 450) {                 // V B-fragments
    ushort_t* vf = (ushort_t*)(ws + WS_VFRAG);
    int idx = (bx-400)*256 + tid;        // < 12800
    int jj = idx & 7, lane = (idx>>3) & 63, c = idx >> 9;
    int h = c*32 + ((lane>>4)<<3) + jj;
    int n = lane & 15;
    vf[idx] = (h < 798 && n < 12) ? (ushort_t)f2b(vw[h*12 + n]) : (ushort_t)0;
  } else if (bx < 706) {                 // ner = embed@linear_w + b (one wave per row)
    float* ner = (float*)(ws + WS_NER);
    int w = tid >> 6, lane = tid & 63;
    int row = (bx-450)*4 + w;            // < 1024
    float acc[9];
    #pragma unroll
    for (int i=0;i<9;i++) acc[i]=0.f;
    const float* erow = embed + row*768;
    for (int kk=0; kk<12; kk++) {
      int k = kk*64 + lane;
      float e = erow[k];
      #pragma unroll
      for (int i=0;i<9;i++) acc[i] = __builtin_fmaf(e, lw[k*9+i], acc[i]);
    }
    #pragma unroll
    for (int i=0;i<9;i++) {
      float v = acc[i];
      for (int off=32; off>0; off>>=1) v += __shfl_down(v, off);
      if (lane == 0) ner[row*9+i] = v + lb[i];
    }
  } else {                               // lab2[g][n] = label_emb[g] @ [U|W][768:798, n]
    float* lab2 = (float*)(ws + WS_LAB2);
    int idx = (bx-706)*256 + tid;
    if (idx < 14400) {
      int g = idx / 1600, n = idx - g*1600;
      const float* X = (n < 800) ? uw : ww;
      int nn = (n < 800) ? n : (n - 800);
      float v = 0.f;
      if (nn < 798) {
        float s = 0.f;
        for (int l=0;l<30;l++)
          s = __builtin_fmaf(lemb[g*30+l], X[(768+l)*798 + nn], s);
        v = s;
      }
      lab2[idx] = v;
    }
  }
}

// ---------------------------------------------------- K2: Viterbi (1 block)
__global__ __launch_bounds__(256) void viterbi_kernel(
    const float* __restrict__ start_t, const float* __restrict__ trans,
    const float* __restrict__ end_t,
    char* __restrict__ ws, float* __restrict__ out_tags)
{
  __shared__ char smem[55296];
  // scores[4][256][9] f32 (36864B) | bufA u8 @36864 (9180B) | bufB u8 @46048
  // trl[81] f32 aliases bufB (dead after hist pass) | lastArr @55232
  float* scores = (float*)smem;
  unsigned char* bufA = (unsigned char*)(smem + 36864);
  unsigned char* bufB = (unsigned char*)(smem + 46048);
  float* trl = (float*)(smem + 46048);
  int* lastArr = (int*)(smem + 55232);
  const float* ner = (const float*)(ws + WS_NER);
  int* tags = (int*)(ws + WS_TAGS);
  int tid = threadIdx.x;

  int w = tid>>6, lane = tid&63;
  int b = w;
  int tt = lane < 9 ? lane : 8;
  if (tid < 81) trl[tid] = trans[tid];

  float tcol[9];
  #pragma unroll
  for (int p=0;p<9;p++) tcol[p] = trans[p*9+tt];
  const float* nb = ner + (b*256)*9 + tt;

  float score = start_t[tt] + nb[0];
  if (lane < 9) scores[(b*256 + 0)*9 + tt] = score;

  float cur[15], nxt[15];
  #pragma unroll
  for (int j=0;j<15;j++) cur[j] = nb[(1+j)*9];
  #define RL(p) (__uint_as_float(__builtin_amdgcn_readlane(__float_as_uint(score), p)) + tcol[p])
  for (int ch=0; ch<17; ch++) {
    int sb = 1 + ch*15;
    if (ch < 16) {
      #pragma unroll
      for (int j=0;j<15;j++) nxt[j] = nb[(sb+15+j)*9];
    }
    #pragma unroll
    for (int j=0;j<15;j++) {
      float m0 = fmaxf(fmaxf(RL(0),RL(1)),RL(2));
      float m1 = fmaxf(fmaxf(RL(3),RL(4)),RL(5));
      float m2 = fmaxf(fmaxf(RL(6),RL(7)),RL(8));
      score = fmaxf(fmaxf(m0,m1),m2) + cur[j];
      if (lane < 9) scores[(b*256 + sb + j)*9 + tt] = score;
    }
    #pragma unroll
    for (int j=0;j<15;j++) cur[j] = nxt[j];
  }
  {
    float fin = score + end_t[tt];
    #define RLF(p) __uint_as_float(__builtin_amdgcn_readlane(__float_as_uint(fin), p))
    float bv = RLF(0); int ba = 0;
    #pragma unroll
    for (int p=1;p<9;p++) { float v = RLF(p); if (v > bv) { bv = v; ba = p; } }
    if (lane == 0) lastArr[b] = ba;
    #undef RLF
  }
  #undef RL
  __syncthreads();

  // hist: funcs[b][s][t] = argmax_p(scores[b][s][p] + trans[p][t]), s in [0,254]
  for (int idx = tid; idx < 9180; idx += 256) {
    int bb = idx / 2295, r = idx - bb*2295;
    int s = r / 9, t = r - s*9;
    const float* srow = &scores[(bb*256 + s)*9];
    float best = srow[0] + trl[t]; int arg = 0;
    #pragma unroll
    for (int p=1;p<9;p++) {
      float v = srow[p] + trl[p*9 + t];
      if (v > best) { best = v; arg = p; }
    }
    bufA[idx] = (unsigned char)arg;
  }
  __syncthreads();

  // suffix scan of function composition
  unsigned char* curb = bufA; unsigned char* nxtb = bufB;
  for (int d=1; d<255; d<<=1) {
    for (int idx = tid; idx < 9180; idx += 256) {
      int bb = idx / 2295, r = idx - bb*2295;
      int s = r / 9, t = r - s*9;
      unsigned char v;
      if (s + d <= 254) {
        unsigned char tm = curb[bb*2295 + (s+d)*9 + t];
        v = curb[bb*2295 + s*9 + tm];
      } else v = curb[idx];
      nxtb[idx] = v;
    }
    __syncthreads();
    unsigned char* tmp = curb; curb = nxtb; nxtb = tmp;
  }

  for (int idx = tid; idx < 1024; idx += 256) {
    int bb = idx >> 8, s = idx & 255;
    int last = lastArr[bb];
    int tg = (s == 255) ? last : (int)curb[bb*2295 + s*9 + last];
    tags[idx] = tg;
    out_tags[idx] = (float)tg;
  }
}

// --------------------------------------------------------------- scorer ----
// scores[b,i,j,r] = sum_h tanh(u[b,i,h]+w[b,j,h]) * V[h,r]; diag(none_idx)=100
__global__ __launch_bounds__(256) void scorer_kernel(
    char* __restrict__ ws, const int* __restrict__ none_p,
    float* __restrict__ d_out)
{
  __shared__ ushort_t su[8][804];
  __shared__ ushort_t sw[16][804];
  const ushort_t* uw2 = (const ushort_t*)(ws + WS_UW2);
  const float* lab2   = (const float*)(ws + WS_LAB2);
  const ushort_t* vf  = (const ushort_t*)(ws + WS_VFRAG);
  const int* tags     = (const int*)(ws + WS_TAGS);
  float* out_sc = d_out + 1024;
  int bx = blockIdx.x, tid = threadIdx.x;
  int b = bx >> 9, ti = (bx>>4)&31, tj = bx&15;
  int I0 = ti*8, J0 = tj*16, bS = b*256;

  for (int idx = tid; idx < 800; idx += 256) {    // stage su = u + lab2[tag] (bf16)
    int row = idx / 100, c8 = idx - row*100, kc = c8*8;
    int grow = bS + I0 + row;
    int tag = tags[grow];
    i32x4 uv = *(const i32x4*)(uw2 + (size_t)grow*1600 + kc);
    const float* lp = lab2 + tag*1600 + kc;
    f32x4 l0 = *(const f32x4*)lp;
    f32x4 l1 = *(const f32x4*)(lp+4);
    i32x4 q = (i32x4){ (int)pkbf16(hi16(uv.x)+l0.y, lo16(uv.x)+l0.x),
                       (int)pkbf16(hi16(uv.y)+l0.w, lo16(uv.y)+l0.z),
                       (int)pkbf16(hi16(uv.z)+l1.y, lo16(uv.z)+l1.x),
                       (int)pkbf16(hi16(uv.w)+l1.w, lo16(uv.w)+l1.z) };
    *(i32x4*)&su[row][kc] = q;
  }
  for (int idx = tid; idx < 1600; idx += 256) {   // stage sw = w + lab2[tag] (bf16)
    int row = idx / 100, c8 = idx - row*100, kc = c8*8;
    int grow = bS + J0 + row;
    int tag = tags[grow];
    i32x4 uv = *(const i32x4*)(uw2 + (size_t)grow*1600 + 800 + kc);
    const float* lp = lab2 + tag*1600 + 800 + kc;
    f32x4 l0 = *(const f32x4*)lp;
    f32x4 l1 = *(const f32x4*)(lp+4);
    i32x4 q = (i32x4){ (int)pkbf16(hi16(uv.x)+l0.y, lo16(uv.x)+l0.x),
                       (int)pkbf16(hi16(uv.y)+l0.w, lo16(uv.y)+l0.z),
                       (int)pkbf16(hi16(uv.z)+l1.y, lo16(uv.z)+l1.x),
                       (int)pkbf16(hi16(uv.w)+l1.w, lo16(uv.w)+l1.z) };
    *(i32x4*)&sw[row][kc] = q;
  }
  __syncthreads();

  int lane = tid & 63, w = tid >> 6;
  int m16 = lane & 15, quad = lane >> 4;
  int none = *none_p;

  f32x4 acc[2];
  acc[0] = (f32x4){0.f,0.f,0.f,0.f};
  acc[1] = (f32x4){0.f,0.f,0.f,0.f};

  const ushort_t* vlane = vf + lane*8;
  i32x4 bfc = *(const i32x4*)vlane;
  for (int c=0; c<25; c++) {
    i32x4 bfn;
    if (c < 24) bfn = *(const i32x4*)(vlane + (c+1)*512);
    int koff = c*32 + quad*8;
    i32x4 wv = *(const i32x4*)&sw[m16][koff];
    bf16x8 bfrag = __builtin_bit_cast(bf16x8, bfc);
    #pragma unroll
    for (int it=0; it<2; it++) {
      i32x4 uv = *(const i32x4*)&su[w*2+it][koff];
      unsigned a0 = pkbf16(tanh_pade(hi16g(uv.x)+hi16g(wv.x)), tanh_pade(lo16(uv.x)+lo16(wv.x)));
      unsigned a1 = pkbf16(tanh_pade(hi16g(uv.y)+hi16g(wv.y)), tanh_pade(lo16(uv.y)+lo16(wv.y)));
      unsigned a2 = pkbf16(tanh_pade(hi16g(uv.z)+hi16g(wv.z)), tanh_pade(lo16(uv.z)+lo16(wv.z)));
      unsigned a3 = pkbf16(tanh_pade(hi16g(uv.w)+hi16g(wv.w)), tanh_pade(lo16(uv.w)+lo16(wv.w)));
      i32x4 avv = (i32x4){(int)a0,(int)a1,(int)a2,(int)a3};
      bf16x8 af = __builtin_bit_cast(bf16x8, avv);
      acc[it] = __builtin_amdgcn_mfma_f32_16x16x32_bf16(af, bfrag, acc[it], 0,0,0);
    }
    bfc = bfn;
  }

  int r = m16;                         // D: col=lane&15 -> r, row=quad*4+reg -> j_local
  if (r < 12) {
    #pragma unroll
    for (int it=0; it<2; it++) {
      int gi = I0 + w*2 + it;
      #pragma unroll
      for (int reg=0; reg<4; reg++) {
        int gj = J0 + quad*4 + reg;
        float v = acc[it][reg];
        if (gi == gj && r == none) v = 100.0f;
        out_sc[(size_t)((bS + gi)*256 + gj)*12 + r] = v;
      }
    }
  }
}

extern "C" void kernel_launch(void* const* d_in, const int* in_sizes, int n_in,
                              void* d_out, int out_size, void* d_ws, size_t ws_size,
                              hipStream_t stream)
{
  const float* embed = (const float*)d_in[0];
  const float* lw    = (const float*)d_in[1];
  const float* lb    = (const float*)d_in[2];
  const float* st    = (const float*)d_in[3];
  const float* tr    = (const float*)d_in[4];
  const float* et    = (const float*)d_in[5];
  const float* lemb  = (const float*)d_in[6];
  const float* uw    = (const float*)d_in[7];
  const float* ub    = (const float*)d_in[8];
  const float* ww    = (const float*)d_in[9];
  const float* wb    = (const float*)d_in[10];
  const float* vw    = (const float*)d_in[11];
  const int* none_p  = (const int*)d_in[12];
  char* ws = (char*)d_ws;
  float* out = (float*)d_out;

  hipLaunchKernelGGL(gemm_prep_kernel, dim3(763), dim3(256), 0, stream,
                     embed, lw, lb, lemb, uw, ub, ww, wb, vw, ws);
  hipLaunchKernelGGL(viterbi_kernel, dim3(1), dim3(256), 0, stream,
                     st, tr, et, ws, out);
  hipLaunchKernelGGL(scorer_kernel, dim3(2048), dim3(256), 0, stream,
                     ws, none_p, out);
}

// Round 9
// 203.311 us; speedup vs baseline: 1.2156x; 1.2156x over previous
//
#include <hip/hip_runtime.h>

// BERT joint NER+relation head on MI355X (gfx950).
// Inputs: fp32. Output: fp32 flat [tags(1024) | scores(3145728)].
// R9: revert scorer to exp2-tanh (R7 known-good 73us); Viterbi backtrace ->
// packed-nibble function composition in registers (scan was ~30us of LDS-
// dependent chases); prep stays merged in GEMM kernel.

typedef unsigned short ushort_t;
typedef __attribute__((ext_vector_type(8))) short bf16x8;
typedef __attribute__((ext_vector_type(4))) float f32x4;
typedef __attribute__((ext_vector_type(4))) int i32x4;
typedef unsigned long long u64;

#define C2F 2.8853900817779268f  // 2*log2(e)

// workspace offsets (bytes), all 16-aligned; total 3,400,960 B
#define WS_UW2   0u         // ushort [1024][1600] : bf16( 2log2e*(embed@[U|W] + bias) )
#define WS_NER   3276800u   // float  [1024][9]
#define WS_VFRAG 3313664u   // ushort [25][64][8]  : V as 16x16x32 B-fragments (bf16)
#define WS_LAB2  3339264u   // float  [9][1600]    : 2log2e*(label_emb@[U|W][768:])
#define WS_TAGS  3396864u   // int    [1024]

__device__ __forceinline__ unsigned f2b(float f){          // RNE, finite only
  unsigned u = __float_as_uint(f);
  return (u + 0x7FFFu + ((u>>16)&1u)) >> 16;
}
__device__ __forceinline__ unsigned pkbf16(float hi, float lo){
  return __builtin_amdgcn_perm(__float_as_uint(hi), __float_as_uint(lo), 0x07060302u);
}
__device__ __forceinline__ float lo16(int v){ return __uint_as_float(((unsigned)v)<<16); }
__device__ __forceinline__ float hi16(int v){ return __uint_as_float(((unsigned)v)&0xFFFF0000u); }
__device__ __forceinline__ float tanh_fast(float x2){  // x2 = 2*log2e*x -> tanh(x)
  float e = __builtin_amdgcn_exp2f(x2);
  float r = __builtin_amdgcn_rcpf(e + 1.0f);
  return __builtin_fmaf(-2.0f, r, 1.0f);
}
// compose packed tag-functions (9 nibbles): R[t] = F[H[t]]
__device__ __forceinline__ u64 fcompose(u64 F, u64 H){
  u64 R = 0;
  #pragma unroll
  for (int t=0;t<9;t++){
    unsigned h = (unsigned)(H >> (4*t)) & 15u;
    unsigned v = (unsigned)(F >> (4*h)) & 15u;
    R |= (u64)v << (4*t);
  }
  return R;
}

// ---------------------------------------- K1: GEMM + prep (763 blocks) ----
// blocks [0,400): GEMM; [400,450): V frags; [450,706): ner; [706,763): lab2
__global__ __launch_bounds__(256) void gemm_prep_kernel(
    const float* __restrict__ embed, const float* __restrict__ lw,
    const float* __restrict__ lb,    const float* __restrict__ lemb,
    const float* __restrict__ uw,    const float* __restrict__ ub,
    const float* __restrict__ ww,    const float* __restrict__ wb,
    const float* __restrict__ vw,    char* __restrict__ ws)
{
  __shared__ char smem[10496];
  int bx = blockIdx.x, tid = threadIdx.x;
  if (bx < 400) {
    ushort_t (*As)[40] = (ushort_t(*)[40])smem;            // [m][k] +8 pad
    ushort_t (*Bs)[42] = (ushort_t(*)[42])(smem + 5120);   // [n][k] +10 pad
    ushort_t* uw2 = (ushort_t*)(ws + WS_UW2);
    int bm = bx & 15, bn = bx >> 4;
    int M0 = bm*64, N0 = bn*64;
    int w = tid>>6, lane = tid&63;
    int wr = w>>1, wc = w&1;
    int m16 = lane&15, quad = lane>>4;
    int nl = tid>>2, k8 = (tid&3)<<3;
    int bnn = tid & 63, bw = tid >> 6;
    int gn = N0 + bnn;
    const float* bsrc = uw; int bcol = 0; bool bzero = true;
    if (gn < 798)                    { bsrc = uw; bcol = gn;     bzero = false; }
    else if (gn >= 800 && gn < 1598) { bsrc = ww; bcol = gn-800; bzero = false; }

    f32x4 acc[2][2];
    #pragma unroll
    for (int mi=0;mi<2;mi++)
      #pragma unroll
      for (int ni=0;ni<2;ni++) acc[mi][ni] = (f32x4){0.f,0.f,0.f,0.f};

    f32x4 a_lo, a_hi; float bvals[8];
    {
      const float* ap = &embed[(M0+nl)*768 + k8];
      a_lo = *(const f32x4*)ap; a_hi = *(const f32x4*)(ap+4);
      #pragma unroll
      for (int r=0;r<4;r++) {
        int kk = r*8 + bw*2;
        bvals[2*r]   = bzero ? 0.f : bsrc[(kk  )*798 + bcol];
        bvals[2*r+1] = bzero ? 0.f : bsrc[(kk+1)*798 + bcol];
      }
    }
    for (int k0=0; k0<768; k0+=32) {
      i32x4 av = (i32x4){ (int)pkbf16(a_lo.y,a_lo.x), (int)pkbf16(a_lo.w,a_lo.z),
                          (int)pkbf16(a_hi.y,a_hi.x), (int)pkbf16(a_hi.w,a_hi.z) };
      *(i32x4*)&As[nl][k8] = av;
      #pragma unroll
      for (int r=0;r<4;r++) {
        int kk = r*8 + bw*2;
        *(unsigned*)&Bs[bnn][kk] = pkbf16(bvals[2*r+1], bvals[2*r]);
      }
      __syncthreads();
      if (k0 + 32 < 768) {
        const float* ap = &embed[(M0+nl)*768 + k0 + 32 + k8];
        a_lo = *(const f32x4*)ap; a_hi = *(const f32x4*)(ap+4);
        #pragma unroll
        for (int r=0;r<4;r++) {
          int kk = r*8 + bw*2;
          bvals[2*r]   = bzero ? 0.f : bsrc[(k0+32+kk  )*798 + bcol];
          bvals[2*r+1] = bzero ? 0.f : bsrc[(k0+32+kk+1)*798 + bcol];
        }
      }
      bf16x8 a0 = *(const bf16x8*)&As[wr*32      + m16][quad*8];
      bf16x8 a1 = *(const bf16x8*)&As[wr*32 + 16 + m16][quad*8];
      bf16x8 b0 = *(const bf16x8*)&Bs[wc*32      + m16][quad*8];
      bf16x8 b1 = *(const bf16x8*)&Bs[wc*32 + 16 + m16][quad*8];
      acc[0][0] = __builtin_amdgcn_mfma_f32_16x16x32_bf16(a0,b0,acc[0][0],0,0,0);
      acc[0][1] = __builtin_amdgcn_mfma_f32_16x16x32_bf16(a0,b1,acc[0][1],0,0,0);
      acc[1][0] = __builtin_amdgcn_mfma_f32_16x16x32_bf16(a1,b0,acc[1][0],0,0,0);
      acc[1][1] = __builtin_amdgcn_mfma_f32_16x16x32_bf16(a1,b1,acc[1][1],0,0,0);
      __syncthreads();
    }
    #pragma unroll
    for (int mi=0;mi<2;mi++)
      #pragma unroll
      for (int ni=0;ni<2;ni++)
        #pragma unroll
        for (int reg=0;reg<4;reg++) {
          int gm = M0 + wr*32 + mi*16 + quad*4 + reg;
          int go = N0 + wc*32 + ni*16 + m16;
          float bias = 0.f;
          if (go < 798) bias = ub[go];
          else if (go >= 800 && go < 1598) bias = wb[go-800];
          float v = (acc[mi][ni][reg] + bias) * C2F;
          uw2[gm*1600 + go] = (ushort_t)f2b(v);
        }
  } else if (bx < 450) {                 // V B-fragments
    ushort_t* vf = (ushort_t*)(ws + WS_VFRAG);
    int idx = (bx-400)*256 + tid;        // < 12800
    int jj = idx & 7, lane = (idx>>3) & 63, c = idx >> 9;
    int h = c*32 + ((lane>>4)<<3) + jj;
    int n = lane & 15;
    vf[idx] = (h < 798 && n < 12) ? (ushort_t)f2b(vw[h*12 + n]) : (ushort_t)0;
  } else if (bx < 706) {                 // ner = embed@linear_w + b (one wave per row)
    float* ner = (float*)(ws + WS_NER);
    int w = tid >> 6, lane = tid & 63;
    int row = (bx-450)*4 + w;            // < 1024
    float acc[9];
    #pragma unroll
    for (int i=0;i<9;i++) acc[i]=0.f;
    const float* erow = embed + row*768;
    for (int kk=0; kk<12; kk++) {
      int k = kk*64 + lane;
      float e = erow[k];
      #pragma unroll
      for (int i=0;i<9;i++) acc[i] = __builtin_fmaf(e, lw[k*9+i], acc[i]);
    }
    #pragma unroll
    for (int i=0;i<9;i++) {
      float v = acc[i];
      for (int off=32; off>0; off>>=1) v += __shfl_down(v, off);
      if (lane == 0) ner[row*9+i] = v + lb[i];
    }
  } else {                               // lab2[g][n] = C2 * (label_emb[g] @ [U|W][768:798, n])
    float* lab2 = (float*)(ws + WS_LAB2);
    int idx = (bx-706)*256 + tid;
    if (idx < 14400) {
      int g = idx / 1600, n = idx - g*1600;
      const float* X = (n < 800) ? uw : ww;
      int nn = (n < 800) ? n : (n - 800);
      float v = 0.f;
      if (nn < 798) {
        float s = 0.f;
        for (int l=0;l<30;l++)
          s = __builtin_fmaf(lemb[g*30+l], X[(768+l)*798 + nn], s);
        v = s * C2F;
      }
      lab2[idx] = v;
    }
  }
}

// ---------------------------------------------------- K2: Viterbi (1 block)
__global__ __launch_bounds__(256) void viterbi_kernel(
    const float* __restrict__ start_t, const float* __restrict__ trans,
    const float* __restrict__ end_t,
    char* __restrict__ ws, float* __restrict__ out_tags)
{
  __shared__ char smem[46848];
  float* scores = (float*)smem;                    // [4][256][9] f32, 36864 B
  u64* pk = (u64*)(smem + 36864);                  // [4][256] packed funcs, 8192 B
  float* trl = (float*)(smem + 45056);             // [81]
  int* lastArr = (int*)(smem + 45384);             // [4]
  unsigned char* tagbuf = (unsigned char*)(smem + 45400);  // [4][256]
  const float* ner = (const float*)(ws + WS_NER);
  int* tags = (int*)(ws + WS_TAGS);
  int tid = threadIdx.x;
  int w = tid>>6, lane = tid&63;
  int b = w;
  int tt = lane < 9 ? lane : 8;
  if (tid < 81) trl[tid] = trans[tid];

  // ---- forward pass (one wave per batch, lanes 0..8 hold tag scores)
  float tcol[9];
  #pragma unroll
  for (int p=0;p<9;p++) tcol[p] = trans[p*9+tt];
  const float* nb = ner + (b*256)*9 + tt;
  float score = start_t[tt] + nb[0];
  if (lane < 9) scores[(b*256 + 0)*9 + tt] = score;

  float cur[15], nxt[15];
  #pragma unroll
  for (int j=0;j<15;j++) cur[j] = nb[(1+j)*9];
  #define RL(p) (__uint_as_float(__builtin_amdgcn_readlane(__float_as_uint(score), p)) + tcol[p])
  for (int ch=0; ch<17; ch++) {
    int sb = 1 + ch*15;
    if (ch < 16) {
      #pragma unroll
      for (int j=0;j<15;j++) nxt[j] = nb[(sb+15+j)*9];
    }
    #pragma unroll
    for (int j=0;j<15;j++) {
      float m0 = fmaxf(fmaxf(RL(0),RL(1)),RL(2));
      float m1 = fmaxf(fmaxf(RL(3),RL(4)),RL(5));
      float m2 = fmaxf(fmaxf(RL(6),RL(7)),RL(8));
      score = fmaxf(fmaxf(m0,m1),m2) + cur[j];
      if (lane < 9) scores[(b*256 + sb + j)*9 + tt] = score;
    }
    #pragma unroll
    for (int j=0;j<15;j++) cur[j] = nxt[j];
  }
  {
    float fin = score + end_t[tt];
    #define RLF(p) __uint_as_float(__builtin_amdgcn_readlane(__float_as_uint(fin), p))
    float bv = RLF(0); int ba = 0;
    #pragma unroll
    for (int p=1;p<9;p++) { float v = RLF(p); if (v > bv) { bv = v; ba = p; } }
    if (lane == 0) lastArr[b] = ba;
    #undef RLF
  }
  #undef RL
  __syncthreads();

  // ---- hist + pack: pk[b][s] = function t -> argmax_p(scores[b][s][p]+trans[p][t])
  for (int idx = tid; idx < 1024; idx += 256) {
    int bb = idx >> 8, s = idx & 255;
    u64 f;
    if (s == 255) f = 0x876543210ULL;              // identity
    else {
      const float* srow = &scores[(bb*256 + s)*9];
      float sp[9];
      #pragma unroll
      for (int p=0;p<9;p++) sp[p] = srow[p];
      f = 0;
      #pragma unroll
      for (int t=0;t<9;t++) {
        float best = sp[0] + trl[t]; int arg = 0;
        #pragma unroll
        for (int p=1;p<9;p++) {
          float v = sp[p] + trl[p*9 + t];
          if (v > best) { best = v; arg = p; }
        }
        f |= (u64)arg << (4*t);
      }
    }
    pk[bb*256 + s] = f;
  }
  __syncthreads();

  // ---- chunked suffix composition + walk, wave 0 only (lane = b*16+c)
  if (tid < 64) {
    int cb = tid >> 4, c = tid & 15;
    u64 fs[16];
    #pragma unroll
    for (int j=0;j<16;j++) fs[j] = pk[cb*256 + c*16 + j];
    u64 G = fs[15];
    #pragma unroll
    for (int j=14;j>=0;j--) G = fcompose(fs[j], G);   // G = f_{16c} o ... o f_{16c+15}
    // suffix scan over 16 chunks within the wave (batches are 16-lane groups)
    u64 F = G;
    #pragma unroll
    for (int d=1; d<16; d<<=1) {
      u64 H = __shfl(F, tid + d);
      if (c + d < 16) F = fcompose(F, H);
    }
    // F maps final tag -> tag at 16c. Need t at 16c+16 = F_{c+1}[last].
    int last = lastArr[cb];
    u64 Hn = __shfl(F, (c==15) ? tid : tid+1);
    unsigned t_cur = (c==15) ? (unsigned)last
                             : (unsigned)((Hn >> (4*last)) & 15u);
    #pragma unroll
    for (int j=15;j>=0;j--) {
      t_cur = (unsigned)((fs[j] >> (4*t_cur)) & 15u);
      tagbuf[cb*256 + c*16 + j] = (unsigned char)t_cur;
    }
  }
  __syncthreads();

  for (int idx = tid; idx < 1024; idx += 256) {
    int tg = (int)tagbuf[idx];
    tags[idx] = tg;
    out_tags[idx] = (float)tg;
  }
}

// --------------------------------------------------------------- scorer ----
// scores[b,i,j,r] = sum_h tanh(u[b,i,h]+w[b,j,h]) * V[h,r]; diag(none_idx)=100
__global__ __launch_bounds__(256) void scorer_kernel(
    char* __restrict__ ws, const int* __restrict__ none_p,
    float* __restrict__ d_out)
{
  __shared__ ushort_t su[8][804];
  __shared__ ushort_t sw[16][804];
  const ushort_t* uw2 = (const ushort_t*)(ws + WS_UW2);
  const float* lab2   = (const float*)(ws + WS_LAB2);
  const ushort_t* vf  = (const ushort_t*)(ws + WS_VFRAG);
  const int* tags     = (const int*)(ws + WS_TAGS);
  float* out_sc = d_out + 1024;
  int bx = blockIdx.x, tid = threadIdx.x;
  int b = bx >> 9, ti = (bx>>4)&31, tj = bx&15;
  int I0 = ti*8, J0 = tj*16, bS = b*256;

  for (int idx = tid; idx < 800; idx += 256) {    // stage su = u2 + lab2[tag] (bf16)
    int row = idx / 100, c8 = idx - row*100, kc = c8*8;
    int grow = bS + I0 + row;
    int tag = tags[grow];
    i32x4 uv = *(const i32x4*)(uw2 + (size_t)grow*1600 + kc);
    const float* lp = lab2 + tag*1600 + kc;
    f32x4 l0 = *(const f32x4*)lp;
    f32x4 l1 = *(const f32x4*)(lp+4);
    i32x4 q = (i32x4){ (int)pkbf16(hi16(uv.x)+l0.y, lo16(uv.x)+l0.x),
                       (int)pkbf16(hi16(uv.y)+l0.w, lo16(uv.y)+l0.z),
                       (int)pkbf16(hi16(uv.z)+l1.y, lo16(uv.z)+l1.x),
                       (int)pkbf16(hi16(uv.w)+l1.w, lo16(uv.w)+l1.z) };
    *(i32x4*)&su[row][kc] = q;
  }
  for (int idx = tid; idx < 1600; idx += 256) {   // stage sw = w2 + lab2[tag] (bf16)
    int row = idx / 100, c8 = idx - row*100, kc = c8*8;
    int grow = bS + J0 + row;
    int tag = tags[grow];
    i32x4 uv = *(const i32x4*)(uw2 + (size_t)grow*1600 + 800 + kc);
    const float* lp = lab2 + tag*1600 + 800 + kc;
    f32x4 l0 = *(const f32x4*)lp;
    f32x4 l1 = *(const f32x4*)(lp+4);
    i32x4 q = (i32x4){ (int)pkbf16(hi16(uv.x)+l0.y, lo16(uv.x)+l0.x),
                       (int)pkbf16(hi16(uv.y)+l0.w, lo16(uv.y)+l0.z),
                       (int)pkbf16(hi16(uv.z)+l1.y, lo16(uv.z)+l1.x),
                       (int)pkbf16(hi16(uv.w)+l1.w, lo16(uv.w)+l1.z) };
    *(i32x4*)&sw[row][kc] = q;
  }
  __syncthreads();

  int lane = tid & 63, w = tid >> 6;
  int m16 = lane & 15, quad = lane >> 4;
  int none = *none_p;

  f32x4 acc[2];
  acc[0] = (f32x4){0.f,0.f,0.f,0.f};
  acc[1] = (f32x4){0.f,0.f,0.f,0.f};

  const ushort_t* vlane = vf + lane*8;
  i32x4 bfc = *(const i32x4*)vlane;
  for (int c=0; c<25; c++) {
    i32x4 bfn;
    if (c < 24) bfn = *(const i32x4*)(vlane + (c+1)*512);
    int koff = c*32 + quad*8;
    i32x4 wv = *(const i32x4*)&sw[m16][koff];
    bf16x8 bfrag = __builtin_bit_cast(bf16x8, bfc);
    #pragma unroll
    for (int it=0; it<2; it++) {
      i32x4 uv = *(const i32x4*)&su[w*2+it][koff];
      unsigned a0 = pkbf16(tanh_fast(hi16(uv.x)+hi16(wv.x)), tanh_fast(lo16(uv.x)+lo16(wv.x)));
      unsigned a1 = pkbf16(tanh_fast(hi16(uv.y)+hi16(wv.y)), tanh_fast(lo16(uv.y)+lo16(wv.y)));
      unsigned a2 = pkbf16(tanh_fast(hi16(uv.z)+hi16(wv.z)), tanh_fast(lo16(uv.z)+lo16(wv.z)));
      unsigned a3 = pkbf16(tanh_fast(hi16(uv.w)+hi16(wv.w)), tanh_fast(lo16(uv.w)+lo16(wv.w)));
      i32x4 avv = (i32x4){(int)a0,(int)a1,(int)a2,(int)a3};
      bf16x8 af = __builtin_bit_cast(bf16x8, avv);
      acc[it] = __builtin_amdgcn_mfma_f32_16x16x32_bf16(af, bfrag, acc[it], 0,0,0);
    }
    bfc = bfn;
  }

  int r = m16;                         // D: col=lane&15 -> r, row=quad*4+reg -> j_local
  if (r < 12) {
    #pragma unroll
    for (int it=0; it<2; it++) {
      int gi = I0 + w*2 + it;
      #pragma unroll
      for (int reg=0; reg<4; reg++) {
        int gj = J0 + quad*4 + reg;
        float v = acc[it][reg];
        if (gi == gj && r == none) v = 100.0f;
        out_sc[(size_t)((bS + gi)*256 + gj)*12 + r] = v;
      }
    }
  }
}

extern "C" void kernel_launch(void* const* d_in, const int* in_sizes, int n_in,
                              void* d_out, int out_size, void* d_ws, size_t ws_size,
                              hipStream_t stream)
{
  const float* embed = (const float*)d_in[0];
  const float* lw    = (const float*)d_in[1];
  const float* lb    = (const float*)d_in[2];
  const float* st    = (const float*)d_in[3];
  const float* tr    = (const float*)d_in[4];
  const float* et    = (const float*)d_in[5];
  const float* lemb  = (const float*)d_in[6];
  const float* uw    = (const float*)d_in[7];
  const float* ub    = (const float*)d_in[8];
  const float* ww    = (const float*)d_in[9];
  const float* wb    = (const float*)d_in[10];
  const float* vw    = (const float*)d_in[11];
  const int* none_p  = (const int*)d_in[12];
  char* ws = (char*)d_ws;
  float* out = (float*)d_out;

  hipLaunchKernelGGL(gemm_prep_kernel, dim3(763), dim3(256), 0, stream,
                     embed, lw, lb, lemb, uw, ub, ww, wb, vw, ws);
  hipLaunchKernelGGL(viterbi_kernel, dim3(1), dim3(256), 0, stream,
                     st, tr, et, ws, out);
  hipLaunchKernelGGL(scorer_kernel, dim3(2048), dim3(256), 0, stream,
                     ws, none_p, out);
}

// Round 10
// 193.251 us; speedup vs baseline: 1.2789x; 1.0521x over previous
//
#include <hip/hip_runtime.h>

// BERT joint NER+relation head on MI355X (gfx950).
// Inputs: fp32. Output: fp32 flat [tags(1024) | scores(3145728)].
// R10: scorer math rework - tanh = 1-2r folded into epilogue (colsum trick,
// r fed to MFMA directly), float2 packed adds (v_pk_add_f32), unmasked hi
// extract. Everything else = R9 (known-good).

typedef unsigned short ushort_t;
typedef __attribute__((ext_vector_type(8))) short bf16x8;
typedef __attribute__((ext_vector_type(4))) float f32x4;
typedef __attribute__((ext_vector_type(2))) float f32x2;
typedef __attribute__((ext_vector_type(4))) int i32x4;
typedef unsigned long long u64;

#define C2F 2.8853900817779268f  // 2*log2(e)

// workspace offsets (bytes), all 16-aligned; total 3,401,024 B
#define WS_UW2   0u         // ushort [1024][1600] : bf16( 2log2e*(embed@[U|W] + bias) )
#define WS_NER   3276800u   // float  [1024][9]
#define WS_VFRAG 3313664u   // ushort [25][64][8]  : V as 16x16x32 B-fragments (bf16)
#define WS_LAB2  3339264u   // float  [9][1600]    : 2log2e*(label_emb@[U|W][768:])
#define WS_TAGS  3396864u   // int    [1024]
#define WS_CSUM  3400960u   // float  [12]         : colsum_r = sum_h V[h,r]

__device__ __forceinline__ unsigned f2b(float f){          // RNE, finite only
  unsigned u = __float_as_uint(f);
  return (u + 0x7FFFu + ((u>>16)&1u)) >> 16;
}
__device__ __forceinline__ unsigned pkbf16(float hi, float lo){
  return __builtin_amdgcn_perm(__float_as_uint(hi), __float_as_uint(lo), 0x07060302u);
}
__device__ __forceinline__ float lo16(int v){ return __uint_as_float(((unsigned)v)<<16); }
__device__ __forceinline__ float hi16(int v){ return __uint_as_float(((unsigned)v)&0xFFFF0000u); }
// hi half WITHOUT masking low bits: rel err < 2^-8 ~ bf16 noise (validated R8)
__device__ __forceinline__ float hi16g(int v){ return __uint_as_float((unsigned)v); }
__device__ __forceinline__ float tanh_fast(float x2){  // staging-path tanh
  float e = __builtin_amdgcn_exp2f(x2);
  float r = __builtin_amdgcn_rcpf(e + 1.0f);
  return __builtin_fmaf(-2.0f, r, 1.0f);
}
// compose packed tag-functions (9 nibbles): R[t] = F[H[t]]
__device__ __forceinline__ u64 fcompose(u64 F, u64 H){
  u64 R = 0;
  #pragma unroll
  for (int t=0;t<9;t++){
    unsigned h = (unsigned)(H >> (4*t)) & 15u;
    unsigned v = (unsigned)(F >> (4*h)) & 15u;
    R |= (u64)v << (4*t);
  }
  return R;
}

// ---------------------------------------- K1: GEMM + prep (764 blocks) ----
// [0,400): GEMM; [400,450): V frags; [450,706): ner; [706,763): lab2; 763: csum
__global__ __launch_bounds__(256) void gemm_prep_kernel(
    const float* __restrict__ embed, const float* __restrict__ lw,
    const float* __restrict__ lb,    const float* __restrict__ lemb,
    const float* __restrict__ uw,    const float* __restrict__ ub,
    const float* __restrict__ ww,    const float* __restrict__ wb,
    const float* __restrict__ vw,    char* __restrict__ ws)
{
  __shared__ char smem[10496];
  int bx = blockIdx.x, tid = threadIdx.x;
  if (bx < 400) {
    ushort_t (*As)[40] = (ushort_t(*)[40])smem;            // [m][k] +8 pad
    ushort_t (*Bs)[42] = (ushort_t(*)[42])(smem + 5120);   // [n][k] +10 pad
    ushort_t* uw2 = (ushort_t*)(ws + WS_UW2);
    int bm = bx & 15, bn = bx >> 4;
    int M0 = bm*64, N0 = bn*64;
    int w = tid>>6, lane = tid&63;
    int wr = w>>1, wc = w&1;
    int m16 = lane&15, quad = lane>>4;
    int nl = tid>>2, k8 = (tid&3)<<3;
    int bnn = tid & 63, bw = tid >> 6;
    int gn = N0 + bnn;
    const float* bsrc = uw; int bcol = 0; bool bzero = true;
    if (gn < 798)                    { bsrc = uw; bcol = gn;     bzero = false; }
    else if (gn >= 800 && gn < 1598) { bsrc = ww; bcol = gn-800; bzero = false; }

    f32x4 acc[2][2];
    #pragma unroll
    for (int mi=0;mi<2;mi++)
      #pragma unroll
      for (int ni=0;ni<2;ni++) acc[mi][ni] = (f32x4){0.f,0.f,0.f,0.f};

    f32x4 a_lo, a_hi; float bvals[8];
    {
      const float* ap = &embed[(M0+nl)*768 + k8];
      a_lo = *(const f32x4*)ap; a_hi = *(const f32x4*)(ap+4);
      #pragma unroll
      for (int r=0;r<4;r++) {
        int kk = r*8 + bw*2;
        bvals[2*r]   = bzero ? 0.f : bsrc[(kk  )*798 + bcol];
        bvals[2*r+1] = bzero ? 0.f : bsrc[(kk+1)*798 + bcol];
      }
    }
    for (int k0=0; k0<768; k0+=32) {
      i32x4 av = (i32x4){ (int)pkbf16(a_lo.y,a_lo.x), (int)pkbf16(a_lo.w,a_lo.z),
                          (int)pkbf16(a_hi.y,a_hi.x), (int)pkbf16(a_hi.w,a_hi.z) };
      *(i32x4*)&As[nl][k8] = av;
      #pragma unroll
      for (int r=0;r<4;r++) {
        int kk = r*8 + bw*2;
        *(unsigned*)&Bs[bnn][kk] = pkbf16(bvals[2*r+1], bvals[2*r]);
      }
      __syncthreads();
      if (k0 + 32 < 768) {
        const float* ap = &embed[(M0+nl)*768 + k0 + 32 + k8];
        a_lo = *(const f32x4*)ap; a_hi = *(const f32x4*)(ap+4);
        #pragma unroll
        for (int r=0;r<4;r++) {
          int kk = r*8 + bw*2;
          bvals[2*r]   = bzero ? 0.f : bsrc[(k0+32+kk  )*798 + bcol];
          bvals[2*r+1] = bzero ? 0.f : bsrc[(k0+32+kk+1)*798 + bcol];
        }
      }
      bf16x8 a0 = *(const bf16x8*)&As[wr*32      + m16][quad*8];
      bf16x8 a1 = *(const bf16x8*)&As[wr*32 + 16 + m16][quad*8];
      bf16x8 b0 = *(const bf16x8*)&Bs[wc*32      + m16][quad*8];
      bf16x8 b1 = *(const bf16x8*)&Bs[wc*32 + 16 + m16][quad*8];
      acc[0][0] = __builtin_amdgcn_mfma_f32_16x16x32_bf16(a0,b0,acc[0][0],0,0,0);
      acc[0][1] = __builtin_amdgcn_mfma_f32_16x16x32_bf16(a0,b1,acc[0][1],0,0,0);
      acc[1][0] = __builtin_amdgcn_mfma_f32_16x16x32_bf16(a1,b0,acc[1][0],0,0,0);
      acc[1][1] = __builtin_amdgcn_mfma_f32_16x16x32_bf16(a1,b1,acc[1][1],0,0,0);
      __syncthreads();
    }
    #pragma unroll
    for (int mi=0;mi<2;mi++)
      #pragma unroll
      for (int ni=0;ni<2;ni++)
        #pragma unroll
        for (int reg=0;reg<4;reg++) {
          int gm = M0 + wr*32 + mi*16 + quad*4 + reg;
          int go = N0 + wc*32 + ni*16 + m16;
          float bias = 0.f;
          if (go < 798) bias = ub[go];
          else if (go >= 800 && go < 1598) bias = wb[go-800];
          float v = (acc[mi][ni][reg] + bias) * C2F;
          uw2[gm*1600 + go] = (ushort_t)f2b(v);
        }
  } else if (bx < 450) {                 // V B-fragments
    ushort_t* vf = (ushort_t*)(ws + WS_VFRAG);
    int idx = (bx-400)*256 + tid;        // < 12800
    int jj = idx & 7, lane = (idx>>3) & 63, c = idx >> 9;
    int h = c*32 + ((lane>>4)<<3) + jj;
    int n = lane & 15;
    vf[idx] = (h < 798 && n < 12) ? (ushort_t)f2b(vw[h*12 + n]) : (ushort_t)0;
  } else if (bx < 706) {                 // ner = embed@linear_w + b (one wave per row)
    float* ner = (float*)(ws + WS_NER);
    int w = tid >> 6, lane = tid & 63;
    int row = (bx-450)*4 + w;            // < 1024
    float acc[9];
    #pragma unroll
    for (int i=0;i<9;i++) acc[i]=0.f;
    const float* erow = embed + row*768;
    for (int kk=0; kk<12; kk++) {
      int k = kk*64 + lane;
      float e = erow[k];
      #pragma unroll
      for (int i=0;i<9;i++) acc[i] = __builtin_fmaf(e, lw[k*9+i], acc[i]);
    }
    #pragma unroll
    for (int i=0;i<9;i++) {
      float v = acc[i];
      for (int off=32; off>0; off>>=1) v += __shfl_down(v, off);
      if (lane == 0) ner[row*9+i] = v + lb[i];
    }
  } else if (bx < 763) {                 // lab2[g][n] = C2 * (label_emb[g] @ [U|W][768:798, n])
    float* lab2 = (float*)(ws + WS_LAB2);
    int idx = (bx-706)*256 + tid;
    if (idx < 14400) {
      int g = idx / 1600, n = idx - g*1600;
      const float* X = (n < 800) ? uw : ww;
      int nn = (n < 800) ? n : (n - 800);
      float v = 0.f;
      if (nn < 798) {
        float s = 0.f;
        for (int l=0;l<30;l++)
          s = __builtin_fmaf(lemb[g*30+l], X[(768+l)*798 + nn], s);
        v = s * C2F;
      }
      lab2[idx] = v;
    }
  } else {                               // csum[r] = sum_h V[h,r]
    float* csum = (float*)(ws + WS_CSUM);
    if (tid < 12) {
      float s = 0.f;
      for (int h=0;h<798;h++) s += vw[h*12 + tid];
      csum[tid] = s;
    }
  }
}

// ---------------------------------------------------- K2: Viterbi (1 block)
__global__ __launch_bounds__(256) void viterbi_kernel(
    const float* __restrict__ start_t, const float* __restrict__ trans,
    const float* __restrict__ end_t,
    char* __restrict__ ws, float* __restrict__ out_tags)
{
  __shared__ char smem[46848];
  float* scores = (float*)smem;                    // [4][256][9] f32, 36864 B
  u64* pk = (u64*)(smem + 36864);                  // [4][256] packed funcs
  float* trl = (float*)(smem + 45056);             // [81]
  int* lastArr = (int*)(smem + 45384);             // [4]
  unsigned char* tagbuf = (unsigned char*)(smem + 45400);  // [4][256]
  const float* ner = (const float*)(ws + WS_NER);
  int* tags = (int*)(ws + WS_TAGS);
  int tid = threadIdx.x;
  int w = tid>>6, lane = tid&63;
  int b = w;
  int tt = lane < 9 ? lane : 8;
  if (tid < 81) trl[tid] = trans[tid];

  float tcol[9];
  #pragma unroll
  for (int p=0;p<9;p++) tcol[p] = trans[p*9+tt];
  const float* nb = ner + (b*256)*9 + tt;
  float score = start_t[tt] + nb[0];
  if (lane < 9) scores[(b*256 + 0)*9 + tt] = score;

  float cur[15], nxt[15];
  #pragma unroll
  for (int j=0;j<15;j++) cur[j] = nb[(1+j)*9];
  #define RL(p) (__uint_as_float(__builtin_amdgcn_readlane(__float_as_uint(score), p)) + tcol[p])
  for (int ch=0; ch<17; ch++) {
    int sb = 1 + ch*15;
    if (ch < 16) {
      #pragma unroll
      for (int j=0;j<15;j++) nxt[j] = nb[(sb+15+j)*9];
    }
    #pragma unroll
    for (int j=0;j<15;j++) {
      float m0 = fmaxf(fmaxf(RL(0),RL(1)),RL(2));
      float m1 = fmaxf(fmaxf(RL(3),RL(4)),RL(5));
      float m2 = fmaxf(fmaxf(RL(6),RL(7)),RL(8));
      score = fmaxf(fmaxf(m0,m1),m2) + cur[j];
      if (lane < 9) scores[(b*256 + sb + j)*9 + tt] = score;
    }
    #pragma unroll
    for (int j=0;j<15;j++) cur[j] = nxt[j];
  }
  {
    float fin = score + end_t[tt];
    #define RLF(p) __uint_as_float(__builtin_amdgcn_readlane(__float_as_uint(fin), p))
    float bv = RLF(0); int ba = 0;
    #pragma unroll
    for (int p=1;p<9;p++) { float v = RLF(p); if (v > bv) { bv = v; ba = p; } }
    if (lane == 0) lastArr[b] = ba;
    #undef RLF
  }
  #undef RL
  __syncthreads();

  for (int idx = tid; idx < 1024; idx += 256) {
    int bb = idx >> 8, s = idx & 255;
    u64 f;
    if (s == 255) f = 0x876543210ULL;              // identity
    else {
      const float* srow = &scores[(bb*256 + s)*9];
      float sp[9];
      #pragma unroll
      for (int p=0;p<9;p++) sp[p] = srow[p];
      f = 0;
      #pragma unroll
      for (int t=0;t<9;t++) {
        float best = sp[0] + trl[t]; int arg = 0;
        #pragma unroll
        for (int p=1;p<9;p++) {
          float v = sp[p] + trl[p*9 + t];
          if (v > best) { best = v; arg = p; }
        }
        f |= (u64)arg << (4*t);
      }
    }
    pk[bb*256 + s] = f;
  }
  __syncthreads();

  if (tid < 64) {
    int cb = tid >> 4, c = tid & 15;
    u64 fs[16];
    #pragma unroll
    for (int j=0;j<16;j++) fs[j] = pk[cb*256 + c*16 + j];
    u64 G = fs[15];
    #pragma unroll
    for (int j=14;j>=0;j--) G = fcompose(fs[j], G);
    u64 F = G;
    #pragma unroll
    for (int d=1; d<16; d<<=1) {
      u64 H = __shfl(F, tid + d);
      if (c + d < 16) F = fcompose(F, H);
    }
    int last = lastArr[cb];
    u64 Hn = __shfl(F, (c==15) ? tid : tid+1);
    unsigned t_cur = (c==15) ? (unsigned)last
                             : (unsigned)((Hn >> (4*last)) & 15u);
    #pragma unroll
    for (int j=15;j>=0;j--) {
      t_cur = (unsigned)((fs[j] >> (4*t_cur)) & 15u);
      tagbuf[cb*256 + c*16 + j] = (unsigned char)t_cur;
    }
  }
  __syncthreads();

  for (int idx = tid; idx < 1024; idx += 256) {
    int tg = (int)tagbuf[idx];
    tags[idx] = tg;
    out_tags[idx] = (float)tg;
  }
}

// --------------------------------------------------------------- scorer ----
// scores[b,i,j,r] = csum[r] - 2*sum_h r(x)*V[h,r], r(x)=rcp(exp2(x2)+1)
__device__ __forceinline__ unsigned rpair(int uvw, int wvw){
  f32x2 xu; xu.x = lo16(uvw); xu.y = hi16g(uvw);
  f32x2 xw; xw.x = lo16(wvw); xw.y = hi16g(wvw);
  f32x2 s = xu + xw;                               // v_pk_add_f32
  float e0 = __builtin_amdgcn_exp2f(s.x);
  float e1 = __builtin_amdgcn_exp2f(s.y);
  f32x2 e; e.x = e0; e.y = e1;
  e = e + (f32x2){1.0f, 1.0f};                     // v_pk_add_f32
  float r0 = __builtin_amdgcn_rcpf(e.x);
  float r1 = __builtin_amdgcn_rcpf(e.y);
  return pkbf16(r1, r0);
}

__global__ __launch_bounds__(256) void scorer_kernel(
    char* __restrict__ ws, const int* __restrict__ none_p,
    float* __restrict__ d_out)
{
  __shared__ ushort_t su[8][804];
  __shared__ ushort_t sw[16][804];
  const ushort_t* uw2 = (const ushort_t*)(ws + WS_UW2);
  const float* lab2   = (const float*)(ws + WS_LAB2);
  const ushort_t* vf  = (const ushort_t*)(ws + WS_VFRAG);
  const int* tags     = (const int*)(ws + WS_TAGS);
  const float* csum   = (const float*)(ws + WS_CSUM);
  float* out_sc = d_out + 1024;
  int bx = blockIdx.x, tid = threadIdx.x;
  int b = bx >> 9, ti = (bx>>4)&31, tj = bx&15;
  int I0 = ti*8, J0 = tj*16, bS = b*256;

  for (int idx = tid; idx < 800; idx += 256) {    // stage su = u2 + lab2[tag] (bf16)
    int row = idx / 100, c8 = idx - row*100, kc = c8*8;
    int grow = bS + I0 + row;
    int tag = tags[grow];
    i32x4 uv = *(const i32x4*)(uw2 + (size_t)grow*1600 + kc);
    const float* lp = lab2 + tag*1600 + kc;
    f32x4 l0 = *(const f32x4*)lp;
    f32x4 l1 = *(const f32x4*)(lp+4);
    i32x4 q = (i32x4){ (int)pkbf16(hi16(uv.x)+l0.y, lo16(uv.x)+l0.x),
                       (int)pkbf16(hi16(uv.y)+l0.w, lo16(uv.y)+l0.z),
                       (int)pkbf16(hi16(uv.z)+l1.y, lo16(uv.z)+l1.x),
                       (int)pkbf16(hi16(uv.w)+l1.w, lo16(uv.w)+l1.z) };
    *(i32x4*)&su[row][kc] = q;
  }
  for (int idx = tid; idx < 1600; idx += 256) {   // stage sw = w2 + lab2[tag] (bf16)
    int row = idx / 100, c8 = idx - row*100, kc = c8*8;
    int grow = bS + J0 + row;
    int tag = tags[grow];
    i32x4 uv = *(const i32x4*)(uw2 + (size_t)grow*1600 + 800 + kc);
    const float* lp = lab2 + tag*1600 + 800 + kc;
    f32x4 l0 = *(const f32x4*)lp;
    f32x4 l1 = *(const f32x4*)(lp+4);
    i32x4 q = (i32x4){ (int)pkbf16(hi16(uv.x)+l0.y, lo16(uv.x)+l0.x),
                       (int)pkbf16(hi16(uv.y)+l0.w, lo16(uv.y)+l0.z),
                       (int)pkbf16(hi16(uv.z)+l1.y, lo16(uv.z)+l1.x),
                       (int)pkbf16(hi16(uv.w)+l1.w, lo16(uv.w)+l1.z) };
    *(i32x4*)&sw[row][kc] = q;
  }
  __syncthreads();

  int lane = tid & 63, w = tid >> 6;
  int m16 = lane & 15, quad = lane >> 4;
  int none = *none_p;

  f32x4 acc[2];
  acc[0] = (f32x4){0.f,0.f,0.f,0.f};
  acc[1] = (f32x4){0.f,0.f,0.f,0.f};

  const ushort_t* vlane = vf + lane*8;
  i32x4 bfc = *(const i32x4*)vlane;
  for (int c=0; c<25; c++) {
    i32x4 bfn;
    if (c < 24) bfn = *(const i32x4*)(vlane + (c+1)*512);
    int koff = c*32 + quad*8;
    i32x4 wv = *(const i32x4*)&sw[m16][koff];
    bf16x8 bfrag = __builtin_bit_cast(bf16x8, bfc);
    #pragma unroll
    for (int it=0; it<2; it++) {
      i32x4 uv = *(const i32x4*)&su[w*2+it][koff];
      unsigned a0 = rpair(uv.x, wv.x);
      unsigned a1 = rpair(uv.y, wv.y);
      unsigned a2 = rpair(uv.z, wv.z);
      unsigned a3 = rpair(uv.w, wv.w);
      i32x4 avv = (i32x4){(int)a0,(int)a1,(int)a2,(int)a3};
      bf16x8 af = __builtin_bit_cast(bf16x8, avv);
      acc[it] = __builtin_amdgcn_mfma_f32_16x16x32_bf16(af, bfrag, acc[it], 0,0,0);
    }
    bfc = bfn;
  }

  int r = m16;                         // D: col=lane&15 -> r, row=quad*4+reg -> j_local
  if (r < 12) {
    float cs = csum[r];
    #pragma unroll
    for (int it=0; it<2; it++) {
      int gi = I0 + w*2 + it;
      #pragma unroll
      for (int reg=0; reg<4; reg++) {
        int gj = J0 + quad*4 + reg;
        float v = __builtin_fmaf(-2.0f, acc[it][reg], cs);
        if (gi == gj && r == none) v = 100.0f;
        out_sc[(size_t)((bS + gi)*256 + gj)*12 + r] = v;
      }
    }
  }
}

extern "C" void kernel_launch(void* const* d_in, const int* in_sizes, int n_in,
                              void* d_out, int out_size, void* d_ws, size_t ws_size,
                              hipStream_t stream)
{
  const float* embed = (const float*)d_in[0];
  const float* lw    = (const float*)d_in[1];
  const float* lb    = (const float*)d_in[2];
  const float* st    = (const float*)d_in[3];
  const float* tr    = (const float*)d_in[4];
  const float* et    = (const float*)d_in[5];
  const float* lemb  = (const float*)d_in[6];
  const float* uw    = (const float*)d_in[7];
  const float* ub    = (const float*)d_in[8];
  const float* ww    = (const float*)d_in[9];
  const float* wb    = (const float*)d_in[10];
  const float* vw    = (const float*)d_in[11];
  const int* none_p  = (const int*)d_in[12];
  char* ws = (char*)d_ws;
  float* out = (float*)d_out;

  hipLaunchKernelGGL(gemm_prep_kernel, dim3(764), dim3(256), 0, stream,
                     embed, lw, lb, lemb, uw, ub, ww, wb, vw, ws);
  hipLaunchKernelGGL(viterbi_kernel, dim3(1), dim3(256), 0, stream,
                     st, tr, et, ws, out);
  hipLaunchKernelGGL(scorer_kernel, dim3(2048), dim3(256), 0, stream,
                     ws, none_p, out);
}

// Round 11
// 180.958 us; speedup vs baseline: 1.3658x; 1.0679x over previous
//
#include <hip/hip_runtime.h>

// BERT joint NER+relation head on MI355X (gfx950).
// Inputs: fp32. Output: fp32 flat [tags(1024) | scores(3145728)].
// R11: exp-product domain - uw2 stores Eu=exp2(C2*(u+bias)), lab2 stores
// exp2(lab2); scorer inner loop is mul+add+2rcp (no exp2). tanh=1-2r via
// csum epilogue (R10). Viterbi/ner unchanged (R9 known-good).

typedef unsigned short ushort_t;
typedef __attribute__((ext_vector_type(8))) short bf16x8;
typedef __attribute__((ext_vector_type(4))) float f32x4;
typedef __attribute__((ext_vector_type(2))) float f32x2;
typedef __attribute__((ext_vector_type(4))) int i32x4;
typedef unsigned long long u64;

#define C2F 2.8853900817779268f  // 2*log2(e)

// workspace offsets (bytes), all 16-aligned; total 3,401,024 B
#define WS_UW2   0u         // ushort [1024][1600] : bf16( exp2(C2*(embed@[U|W]+bias)) )
#define WS_NER   3276800u   // float  [1024][9]
#define WS_VFRAG 3313664u   // ushort [25][64][8]  : V as 16x16x32 B-fragments (bf16)
#define WS_LAB2  3339264u   // float  [9][1600]    : exp2(C2*(label_emb@[U|W][768:]))
#define WS_TAGS  3396864u   // int    [1024]
#define WS_CSUM  3400960u   // float  [12]         : colsum_r = sum_h V[h,r]

__device__ __forceinline__ unsigned f2b(float f){          // RNE, finite only
  unsigned u = __float_as_uint(f);
  return (u + 0x7FFFu + ((u>>16)&1u)) >> 16;
}
__device__ __forceinline__ unsigned pkbf16(float hi, float lo){
  return __builtin_amdgcn_perm(__float_as_uint(hi), __float_as_uint(lo), 0x07060302u);
}
__device__ __forceinline__ float lo16(int v){ return __uint_as_float(((unsigned)v)<<16); }
__device__ __forceinline__ float hi16(int v){ return __uint_as_float(((unsigned)v)&0xFFFF0000u); }
// hi half WITHOUT masking low bits: rel err < 2^-8 ~ bf16 noise (validated R8/R10)
__device__ __forceinline__ float hi16g(int v){ return __uint_as_float((unsigned)v); }
// compose packed tag-functions (9 nibbles): R[t] = F[H[t]]
__device__ __forceinline__ u64 fcompose(u64 F, u64 H){
  u64 R = 0;
  #pragma unroll
  for (int t=0;t<9;t++){
    unsigned h = (unsigned)(H >> (4*t)) & 15u;
    unsigned v = (unsigned)(F >> (4*h)) & 15u;
    R |= (u64)v << (4*t);
  }
  return R;
}

// ---------------------------------------- K1: GEMM + prep (764 blocks) ----
// [0,400): GEMM; [400,450): V frags; [450,706): ner; [706,763): lab2; 763: csum
__global__ __launch_bounds__(256) void gemm_prep_kernel(
    const float* __restrict__ embed, const float* __restrict__ lw,
    const float* __restrict__ lb,    const float* __restrict__ lemb,
    const float* __restrict__ uw,    const float* __restrict__ ub,
    const float* __restrict__ ww,    const float* __restrict__ wb,
    const float* __restrict__ vw,    char* __restrict__ ws)
{
  __shared__ char smem[10496];
  int bx = blockIdx.x, tid = threadIdx.x;
  if (bx < 400) {
    ushort_t (*As)[40] = (ushort_t(*)[40])smem;            // [m][k] +8 pad
    ushort_t (*Bs)[42] = (ushort_t(*)[42])(smem + 5120);   // [n][k] +10 pad
    ushort_t* uw2 = (ushort_t*)(ws + WS_UW2);
    int bm = bx & 15, bn = bx >> 4;
    int M0 = bm*64, N0 = bn*64;
    int w = tid>>6, lane = tid&63;
    int wr = w>>1, wc = w&1;
    int m16 = lane&15, quad = lane>>4;
    int nl = tid>>2, k8 = (tid&3)<<3;
    int bnn = tid & 63, bw = tid >> 6;
    int gn = N0 + bnn;
    const float* bsrc = uw; int bcol = 0; bool bzero = true;
    if (gn < 798)                    { bsrc = uw; bcol = gn;     bzero = false; }
    else if (gn >= 800 && gn < 1598) { bsrc = ww; bcol = gn-800; bzero = false; }

    f32x4 acc[2][2];
    #pragma unroll
    for (int mi=0;mi<2;mi++)
      #pragma unroll
      for (int ni=0;ni<2;ni++) acc[mi][ni] = (f32x4){0.f,0.f,0.f,0.f};

    f32x4 a_lo, a_hi; float bvals[8];
    {
      const float* ap = &embed[(M0+nl)*768 + k8];
      a_lo = *(const f32x4*)ap; a_hi = *(const f32x4*)(ap+4);
      #pragma unroll
      for (int r=0;r<4;r++) {
        int kk = r*8 + bw*2;
        bvals[2*r]   = bzero ? 0.f : bsrc[(kk  )*798 + bcol];
        bvals[2*r+1] = bzero ? 0.f : bsrc[(kk+1)*798 + bcol];
      }
    }
    for (int k0=0; k0<768; k0+=32) {
      i32x4 av = (i32x4){ (int)pkbf16(a_lo.y,a_lo.x), (int)pkbf16(a_lo.w,a_lo.z),
                          (int)pkbf16(a_hi.y,a_hi.x), (int)pkbf16(a_hi.w,a_hi.z) };
      *(i32x4*)&As[nl][k8] = av;
      #pragma unroll
      for (int r=0;r<4;r++) {
        int kk = r*8 + bw*2;
        *(unsigned*)&Bs[bnn][kk] = pkbf16(bvals[2*r+1], bvals[2*r]);
      }
      __syncthreads();
      if (k0 + 32 < 768) {
        const float* ap = &embed[(M0+nl)*768 + k0 + 32 + k8];
        a_lo = *(const f32x4*)ap; a_hi = *(const f32x4*)(ap+4);
        #pragma unroll
        for (int r=0;r<4;r++) {
          int kk = r*8 + bw*2;
          bvals[2*r]   = bzero ? 0.f : bsrc[(k0+32+kk  )*798 + bcol];
          bvals[2*r+1] = bzero ? 0.f : bsrc[(k0+32+kk+1)*798 + bcol];
        }
      }
      bf16x8 a0 = *(const bf16x8*)&As[wr*32      + m16][quad*8];
      bf16x8 a1 = *(const bf16x8*)&As[wr*32 + 16 + m16][quad*8];
      bf16x8 b0 = *(const bf16x8*)&Bs[wc*32      + m16][quad*8];
      bf16x8 b1 = *(const bf16x8*)&Bs[wc*32 + 16 + m16][quad*8];
      acc[0][0] = __builtin_amdgcn_mfma_f32_16x16x32_bf16(a0,b0,acc[0][0],0,0,0);
      acc[0][1] = __builtin_amdgcn_mfma_f32_16x16x32_bf16(a0,b1,acc[0][1],0,0,0);
      acc[1][0] = __builtin_amdgcn_mfma_f32_16x16x32_bf16(a1,b0,acc[1][0],0,0,0);
      acc[1][1] = __builtin_amdgcn_mfma_f32_16x16x32_bf16(a1,b1,acc[1][1],0,0,0);
      __syncthreads();
    }
    #pragma unroll
    for (int mi=0;mi<2;mi++)
      #pragma unroll
      for (int ni=0;ni<2;ni++)
        #pragma unroll
        for (int reg=0;reg<4;reg++) {
          int gm = M0 + wr*32 + mi*16 + quad*4 + reg;
          int go = N0 + wc*32 + ni*16 + m16;
          float bias = 0.f;
          if (go < 798) bias = ub[go];
          else if (go >= 800 && go < 1598) bias = wb[go-800];
          float v = (acc[mi][ni][reg] + bias) * C2F;
          uw2[gm*1600 + go] = (ushort_t)f2b(__builtin_amdgcn_exp2f(v));
        }
  } else if (bx < 450) {                 // V B-fragments
    ushort_t* vf = (ushort_t*)(ws + WS_VFRAG);
    int idx = (bx-400)*256 + tid;        // < 12800
    int jj = idx & 7, lane = (idx>>3) & 63, c = idx >> 9;
    int h = c*32 + ((lane>>4)<<3) + jj;
    int n = lane & 15;
    vf[idx] = (h < 798 && n < 12) ? (ushort_t)f2b(vw[h*12 + n]) : (ushort_t)0;
  } else if (bx < 706) {                 // ner = embed@linear_w + b (one wave per row)
    float* ner = (float*)(ws + WS_NER);
    int w = tid >> 6, lane = tid & 63;
    int row = (bx-450)*4 + w;            // < 1024
    float acc[9];
    #pragma unroll
    for (int i=0;i<9;i++) acc[i]=0.f;
    const float* erow = embed + row*768;
    for (int kk=0; kk<12; kk++) {
      int k = kk*64 + lane;
      float e = erow[k];
      #pragma unroll
      for (int i=0;i<9;i++) acc[i] = __builtin_fmaf(e, lw[k*9+i], acc[i]);
    }
    #pragma unroll
    for (int i=0;i<9;i++) {
      float v = acc[i];
      for (int off=32; off>0; off>>=1) v += __shfl_down(v, off);
      if (lane == 0) ner[row*9+i] = v + lb[i];
    }
  } else if (bx < 763) {                 // lab2[g][n] = exp2(C2 * label_emb[g]@[U|W][768:798,n])
    float* lab2 = (float*)(ws + WS_LAB2);
    int idx = (bx-706)*256 + tid;
    if (idx < 14400) {
      int g = idx / 1600, n = idx - g*1600;
      const float* X = (n < 800) ? uw : ww;
      int nn = (n < 800) ? n : (n - 800);
      float v = 1.0f;                    // pad columns: multiplicative identity
      if (nn < 798) {
        float s = 0.f;
        for (int l=0;l<30;l++)
          s = __builtin_fmaf(lemb[g*30+l], X[(768+l)*798 + nn], s);
        v = __builtin_amdgcn_exp2f(s * C2F);
      }
      lab2[idx] = v;
    }
  } else {                               // csum[r] = sum_h V[h,r]
    float* csum = (float*)(ws + WS_CSUM);
    if (tid < 12) {
      float s = 0.f;
      for (int h=0;h<798;h++) s += vw[h*12 + tid];
      csum[tid] = s;
    }
  }
}

// ---------------------------------------------------- K2: Viterbi (1 block)
__global__ __launch_bounds__(256) void viterbi_kernel(
    const float* __restrict__ start_t, const float* __restrict__ trans,
    const float* __restrict__ end_t,
    char* __restrict__ ws, float* __restrict__ out_tags)
{
  __shared__ char smem[46848];
  float* scores = (float*)smem;                    // [4][256][9] f32, 36864 B
  u64* pk = (u64*)(smem + 36864);                  // [4][256] packed funcs
  float* trl = (float*)(smem + 45056);             // [81]
  int* lastArr = (int*)(smem + 45384);             // [4]
  unsigned char* tagbuf = (unsigned char*)(smem + 45400);  // [4][256]
  const float* ner = (const float*)(ws + WS_NER);
  int* tags = (int*)(ws + WS_TAGS);
  int tid = threadIdx.x;
  int w = tid>>6, lane = tid&63;
  int b = w;
  int tt = lane < 9 ? lane : 8;
  if (tid < 81) trl[tid] = trans[tid];

  float tcol[9];
  #pragma unroll
  for (int p=0;p<9;p++) tcol[p] = trans[p*9+tt];
  const float* nb = ner + (b*256)*9 + tt;
  float score = start_t[tt] + nb[0];
  if (lane < 9) scores[(b*256 + 0)*9 + tt] = score;

  float cur[15], nxt[15];
  #pragma unroll
  for (int j=0;j<15;j++) cur[j] = nb[(1+j)*9];
  #define RL(p) (__uint_as_float(__builtin_amdgcn_readlane(__float_as_uint(score), p)) + tcol[p])
  for (int ch=0; ch<17; ch++) {
    int sb = 1 + ch*15;
    if (ch < 16) {
      #pragma unroll
      for (int j=0;j<15;j++) nxt[j] = nb[(sb+15+j)*9];
    }
    #pragma unroll
    for (int j=0;j<15;j++) {
      float m0 = fmaxf(fmaxf(RL(0),RL(1)),RL(2));
      float m1 = fmaxf(fmaxf(RL(3),RL(4)),RL(5));
      float m2 = fmaxf(fmaxf(RL(6),RL(7)),RL(8));
      score = fmaxf(fmaxf(m0,m1),m2) + cur[j];
      if (lane < 9) scores[(b*256 + sb + j)*9 + tt] = score;
    }
    #pragma unroll
    for (int j=0;j<15;j++) cur[j] = nxt[j];
  }
  {
    float fin = score + end_t[tt];
    #define RLF(p) __uint_as_float(__builtin_amdgcn_readlane(__float_as_uint(fin), p))
    float bv = RLF(0); int ba = 0;
    #pragma unroll
    for (int p=1;p<9;p++) { float v = RLF(p); if (v > bv) { bv = v; ba = p; } }
    if (lane == 0) lastArr[b] = ba;
    #undef RLF
  }
  #undef RL
  __syncthreads();

  for (int idx = tid; idx < 1024; idx += 256) {
    int bb = idx >> 8, s = idx & 255;
    u64 f;
    if (s == 255) f = 0x876543210ULL;              // identity
    else {
      const float* srow = &scores[(bb*256 + s)*9];
      float sp[9];
      #pragma unroll
      for (int p=0;p<9;p++) sp[p] = srow[p];
      f = 0;
      #pragma unroll
      for (int t=0;t<9;t++) {
        float best = sp[0] + trl[t]; int arg = 0;
        #pragma unroll
        for (int p=1;p<9;p++) {
          float v = sp[p] + trl[p*9 + t];
          if (v > best) { best = v; arg = p; }
        }
        f |= (u64)arg << (4*t);
      }
    }
    pk[bb*256 + s] = f;
  }
  __syncthreads();

  if (tid < 64) {
    int cb = tid >> 4, c = tid & 15;
    u64 fs[16];
    #pragma unroll
    for (int j=0;j<16;j++) fs[j] = pk[cb*256 + c*16 + j];
    u64 G = fs[15];
    #pragma unroll
    for (int j=14;j>=0;j--) G = fcompose(fs[j], G);
    u64 F = G;
    #pragma unroll
    for (int d=1; d<16; d<<=1) {
      u64 H = __shfl(F, tid + d);
      if (c + d < 16) F = fcompose(F, H);
    }
    int last = lastArr[cb];
    u64 Hn = __shfl(F, (c==15) ? tid : tid+1);
    unsigned t_cur = (c==15) ? (unsigned)last
                             : (unsigned)((Hn >> (4*last)) & 15u);
    #pragma unroll
    for (int j=15;j>=0;j--) {
      t_cur = (unsigned)((fs[j] >> (4*t_cur)) & 15u);
      tagbuf[cb*256 + c*16 + j] = (unsigned char)t_cur;
    }
  }
  __syncthreads();

  for (int idx = tid; idx < 1024; idx += 256) {
    int tg = (int)tagbuf[idx];
    tags[idx] = tg;
    out_tags[idx] = (float)tg;
  }
}

// --------------------------------------------------------------- scorer ----
// scores = csum[r] - 2*sum_h r*V[h,r], r = rcp(Eu*Ew + 1)  (exp-product domain)
__device__ __forceinline__ unsigned rpair(int uvw, int wvw){
  f32x2 xu; xu.x = lo16(uvw); xu.y = hi16g(uvw);
  f32x2 xw; xw.x = lo16(wvw); xw.y = hi16g(wvw);
  f32x2 p = xu * xw;                               // v_pk_mul_f32
  p = p + (f32x2){1.0f, 1.0f};                     // v_pk_add_f32
  float r0 = __builtin_amdgcn_rcpf(p.x);
  float r1 = __builtin_amdgcn_rcpf(p.y);
  return pkbf16(r1, r0);
}

__global__ __launch_bounds__(256) void scorer_kernel(
    char* __restrict__ ws, const int* __restrict__ none_p,
    float* __restrict__ d_out)
{
  __shared__ ushort_t su[8][804];
  __shared__ ushort_t sw[16][804];
  const ushort_t* uw2 = (const ushort_t*)(ws + WS_UW2);
  const float* lab2   = (const float*)(ws + WS_LAB2);
  const ushort_t* vf  = (const ushort_t*)(ws + WS_VFRAG);
  const int* tags     = (const int*)(ws + WS_TAGS);
  const float* csum   = (const float*)(ws + WS_CSUM);
  float* out_sc = d_out + 1024;
  int bx = blockIdx.x, tid = threadIdx.x;
  int b = bx >> 9, ti = (bx>>4)&31, tj = bx&15;
  int I0 = ti*8, J0 = tj*16, bS = b*256;

  for (int idx = tid; idx < 800; idx += 256) {    // stage su = Eu * Elab[tag] (bf16)
    int row = idx / 100, c8 = idx - row*100, kc = c8*8;
    int grow = bS + I0 + row;
    int tag = tags[grow];
    i32x4 uv = *(const i32x4*)(uw2 + (size_t)grow*1600 + kc);
    const float* lp = lab2 + tag*1600 + kc;
    f32x4 l0 = *(const f32x4*)lp;
    f32x4 l1 = *(const f32x4*)(lp+4);
    i32x4 q = (i32x4){ (int)pkbf16(hi16g(uv.x)*l0.y, lo16(uv.x)*l0.x),
                       (int)pkbf16(hi16g(uv.y)*l0.w, lo16(uv.y)*l0.z),
                       (int)pkbf16(hi16g(uv.z)*l1.y, lo16(uv.z)*l1.x),
                       (int)pkbf16(hi16g(uv.w)*l1.w, lo16(uv.w)*l1.z) };
    *(i32x4*)&su[row][kc] = q;
  }
  for (int idx = tid; idx < 1600; idx += 256) {   // stage sw = Ew * Elab[tag] (bf16)
    int row = idx / 100, c8 = idx - row*100, kc = c8*8;
    int grow = bS + J0 + row;
    int tag = tags[grow];
    i32x4 uv = *(const i32x4*)(uw2 + (size_t)grow*1600 + 800 + kc);
    const float* lp = lab2 + tag*1600 + 800 + kc;
    f32x4 l0 = *(const f32x4*)lp;
    f32x4 l1 = *(const f32x4*)(lp+4);
    i32x4 q = (i32x4){ (int)pkbf16(hi16g(uv.x)*l0.y, lo16(uv.x)*l0.x),
                       (int)pkbf16(hi16g(uv.y)*l0.w, lo16(uv.y)*l0.z),
                       (int)pkbf16(hi16g(uv.z)*l1.y, lo16(uv.z)*l1.x),
                       (int)pkbf16(hi16g(uv.w)*l1.w, lo16(uv.w)*l1.z) };
    *(i32x4*)&sw[row][kc] = q;
  }
  __syncthreads();

  int lane = tid & 63, w = tid >> 6;
  int m16 = lane & 15, quad = lane >> 4;
  int none = *none_p;

  f32x4 acc[2];
  acc[0] = (f32x4){0.f,0.f,0.f,0.f};
  acc[1] = (f32x4){0.f,0.f,0.f,0.f};

  const ushort_t* vlane = vf + lane*8;
  i32x4 bfc = *(const i32x4*)vlane;
  for (int c=0; c<25; c++) {
    i32x4 bfn;
    if (c < 24) bfn = *(const i32x4*)(vlane + (c+1)*512);
    int koff = c*32 + quad*8;
    i32x4 wv = *(const i32x4*)&sw[m16][koff];
    bf16x8 bfrag = __builtin_bit_cast(bf16x8, bfc);
    #pragma unroll
    for (int it=0; it<2; it++) {
      i32x4 uv = *(const i32x4*)&su[w*2+it][koff];
      unsigned a0 = rpair(uv.x, wv.x);
      unsigned a1 = rpair(uv.y, wv.y);
      unsigned a2 = rpair(uv.z, wv.z);
      unsigned a3 = rpair(uv.w, wv.w);
      i32x4 avv = (i32x4){(int)a0,(int)a1,(int)a2,(int)a3};
      bf16x8 af = __builtin_bit_cast(bf16x8, avv);
      acc[it] = __builtin_amdgcn_mfma_f32_16x16x32_bf16(af, bfrag, acc[it], 0,0,0);
    }
    bfc = bfn;
  }

  int r = m16;                         // D: col=lane&15 -> r, row=quad*4+reg -> j_local
  if (r < 12) {
    float cs = csum[r];
    #pragma unroll
    for (int it=0; it<2; it++) {
      int gi = I0 + w*2 + it;
      #pragma unroll
      for (int reg=0; reg<4; reg++) {
        int gj = J0 + quad*4 + reg;
        float v = __builtin_fmaf(-2.0f, acc[it][reg], cs);
        if (gi == gj && r == none) v = 100.0f;
        out_sc[(size_t)((bS + gi)*256 + gj)*12 + r] = v;
      }
    }
  }
}

extern "C" void kernel_launch(void* const* d_in, const int* in_sizes, int n_in,
                              void* d_out, int out_size, void* d_ws, size_t ws_size,
                              hipStream_t stream)
{
  const float* embed = (const float*)d_in[0];
  const float* lw    = (const float*)d_in[1];
  const float* lb    = (const float*)d_in[2];
  const float* st    = (const float*)d_in[3];
  const float* tr    = (const float*)d_in[4];
  const float* et    = (const float*)d_in[5];
  const float* lemb  = (const float*)d_in[6];
  const float* uw    = (const float*)d_in[7];
  const float* ub    = (const float*)d_in[8];
  const float* ww    = (const float*)d_in[9];
  const float* wb    = (const float*)d_in[10];
  const float* vw    = (const float*)d_in[11];
  const int* none_p  = (const int*)d_in[12];
  char* ws = (char*)d_ws;
  float* out = (float*)d_out;

  hipLaunchKernelGGL(gemm_prep_kernel, dim3(764), dim3(256), 0, stream,
                     embed, lw, lb, lemb, uw, ub, ww, wb, vw, ws);
  hipLaunchKernelGGL(viterbi_kernel, dim3(1), dim3(256), 0, stream,
                     st, tr, et, ws, out);
  hipLaunchKernelGGL(scorer_kernel, dim3(2048), dim3(256), 0, stream,
                     ws, none_p, out);
}

// Round 12
// 179.659 us; speedup vs baseline: 1.3757x; 1.0072x over previous
//
#include <hip/hip_runtime.h>

// BERT joint NER+relation head on MI355X (gfx950).
// Inputs: fp32. Output: fp32 flat [tags(1024) | scores(3145728)].
// R12: scorer rcp -> magic+1NR packed reciprocal (8cy vs 16cy/pair).
// Exp-product domain (R11), csum epilogue (R10), Viterbi scan (R9).

typedef unsigned short ushort_t;
typedef __attribute__((ext_vector_type(8))) short bf16x8;
typedef __attribute__((ext_vector_type(4))) float f32x4;
typedef __attribute__((ext_vector_type(2))) float f32x2;
typedef __attribute__((ext_vector_type(4))) int i32x4;
typedef unsigned long long u64;

#define C2F 2.8853900817779268f  // 2*log2(e)

// workspace offsets (bytes), all 16-aligned; total 3,401,024 B
#define WS_UW2   0u         // ushort [1024][1600] : bf16( exp2(C2*(embed@[U|W]+bias)) )
#define WS_NER   3276800u   // float  [1024][9]
#define WS_VFRAG 3313664u   // ushort [25][64][8]  : V as 16x16x32 B-fragments (bf16)
#define WS_LAB2  3339264u   // float  [9][1600]    : exp2(C2*(label_emb@[U|W][768:]))
#define WS_TAGS  3396864u   // int    [1024]
#define WS_CSUM  3400960u   // float  [12]         : colsum_r = sum_h V[h,r]

__device__ __forceinline__ unsigned f2b(float f){          // RNE, finite only
  unsigned u = __float_as_uint(f);
  return (u + 0x7FFFu + ((u>>16)&1u)) >> 16;
}
__device__ __forceinline__ unsigned pkbf16(float hi, float lo){
  return __builtin_amdgcn_perm(__float_as_uint(hi), __float_as_uint(lo), 0x07060302u);
}
__device__ __forceinline__ float lo16(int v){ return __uint_as_float(((unsigned)v)<<16); }
__device__ __forceinline__ float hi16(int v){ return __uint_as_float(((unsigned)v)&0xFFFF0000u); }
// hi half WITHOUT masking low bits: rel err < 2^-8 ~ bf16 noise (validated R8/R10)
__device__ __forceinline__ float hi16g(int v){ return __uint_as_float((unsigned)v); }
// compose packed tag-functions (9 nibbles): R[t] = F[H[t]]
__device__ __forceinline__ u64 fcompose(u64 F, u64 H){
  u64 R = 0;
  #pragma unroll
  for (int t=0;t<9;t++){
    unsigned h = (unsigned)(H >> (4*t)) & 15u;
    unsigned v = (unsigned)(F >> (4*h)) & 15u;
    R |= (u64)v << (4*t);
  }
  return R;
}

// ---------------------------------------- K1: GEMM + prep (764 blocks) ----
// [0,400): GEMM; [400,450): V frags; [450,706): ner; [706,763): lab2; 763: csum
__global__ __launch_bounds__(256) void gemm_prep_kernel(
    const float* __restrict__ embed, const float* __restrict__ lw,
    const float* __restrict__ lb,    const float* __restrict__ lemb,
    const float* __restrict__ uw,    const float* __restrict__ ub,
    const float* __restrict__ ww,    const float* __restrict__ wb,
    const float* __restrict__ vw,    char* __restrict__ ws)
{
  __shared__ char smem[10496];
  int bx = blockIdx.x, tid = threadIdx.x;
  if (bx < 400) {
    ushort_t (*As)[40] = (ushort_t(*)[40])smem;            // [m][k] +8 pad
    ushort_t (*Bs)[42] = (ushort_t(*)[42])(smem + 5120);   // [n][k] +10 pad
    ushort_t* uw2 = (ushort_t*)(ws + WS_UW2);
    int bm = bx & 15, bn = bx >> 4;
    int M0 = bm*64, N0 = bn*64;
    int w = tid>>6, lane = tid&63;
    int wr = w>>1, wc = w&1;
    int m16 = lane&15, quad = lane>>4;
    int nl = tid>>2, k8 = (tid&3)<<3;
    int bnn = tid & 63, bw = tid >> 6;
    int gn = N0 + bnn;
    const float* bsrc = uw; int bcol = 0; bool bzero = true;
    if (gn < 798)                    { bsrc = uw; bcol = gn;     bzero = false; }
    else if (gn >= 800 && gn < 1598) { bsrc = ww; bcol = gn-800; bzero = false; }

    f32x4 acc[2][2];
    #pragma unroll
    for (int mi=0;mi<2;mi++)
      #pragma unroll
      for (int ni=0;ni<2;ni++) acc[mi][ni] = (f32x4){0.f,0.f,0.f,0.f};

    f32x4 a_lo, a_hi; float bvals[8];
    {
      const float* ap = &embed[(M0+nl)*768 + k8];
      a_lo = *(const f32x4*)ap; a_hi = *(const f32x4*)(ap+4);
      #pragma unroll
      for (int r=0;r<4;r++) {
        int kk = r*8 + bw*2;
        bvals[2*r]   = bzero ? 0.f : bsrc[(kk  )*798 + bcol];
        bvals[2*r+1] = bzero ? 0.f : bsrc[(kk+1)*798 + bcol];
      }
    }
    for (int k0=0; k0<768; k0+=32) {
      i32x4 av = (i32x4){ (int)pkbf16(a_lo.y,a_lo.x), (int)pkbf16(a_lo.w,a_lo.z),
                          (int)pkbf16(a_hi.y,a_hi.x), (int)pkbf16(a_hi.w,a_hi.z) };
      *(i32x4*)&As[nl][k8] = av;
      #pragma unroll
      for (int r=0;r<4;r++) {
        int kk = r*8 + bw*2;
        *(unsigned*)&Bs[bnn][kk] = pkbf16(bvals[2*r+1], bvals[2*r]);
      }
      __syncthreads();
      if (k0 + 32 < 768) {
        const float* ap = &embed[(M0+nl)*768 + k0 + 32 + k8];
        a_lo = *(const f32x4*)ap; a_hi = *(const f32x4*)(ap+4);
        #pragma unroll
        for (int r=0;r<4;r++) {
          int kk = r*8 + bw*2;
          bvals[2*r]   = bzero ? 0.f : bsrc[(k0+32+kk  )*798 + bcol];
          bvals[2*r+1] = bzero ? 0.f : bsrc[(k0+32+kk+1)*798 + bcol];
        }
      }
      bf16x8 a0 = *(const bf16x8*)&As[wr*32      + m16][quad*8];
      bf16x8 a1 = *(const bf16x8*)&As[wr*32 + 16 + m16][quad*8];
      bf16x8 b0 = *(const bf16x8*)&Bs[wc*32      + m16][quad*8];
      bf16x8 b1 = *(const bf16x8*)&Bs[wc*32 + 16 + m16][quad*8];
      acc[0][0] = __builtin_amdgcn_mfma_f32_16x16x32_bf16(a0,b0,acc[0][0],0,0,0);
      acc[0][1] = __builtin_amdgcn_mfma_f32_16x16x32_bf16(a0,b1,acc[0][1],0,0,0);
      acc[1][0] = __builtin_amdgcn_mfma_f32_16x16x32_bf16(a1,b0,acc[1][0],0,0,0);
      acc[1][1] = __builtin_amdgcn_mfma_f32_16x16x32_bf16(a1,b1,acc[1][1],0,0,0);
      __syncthreads();
    }
    #pragma unroll
    for (int mi=0;mi<2;mi++)
      #pragma unroll
      for (int ni=0;ni<2;ni++)
        #pragma unroll
        for (int reg=0;reg<4;reg++) {
          int gm = M0 + wr*32 + mi*16 + quad*4 + reg;
          int go = N0 + wc*32 + ni*16 + m16;
          float bias = 0.f;
          if (go < 798) bias = ub[go];
          else if (go >= 800 && go < 1598) bias = wb[go-800];
          float v = (acc[mi][ni][reg] + bias) * C2F;
          uw2[gm*1600 + go] = (ushort_t)f2b(__builtin_amdgcn_exp2f(v));
        }
  } else if (bx < 450) {                 // V B-fragments
    ushort_t* vf = (ushort_t*)(ws + WS_VFRAG);
    int idx = (bx-400)*256 + tid;        // < 12800
    int jj = idx & 7, lane = (idx>>3) & 63, c = idx >> 9;
    int h = c*32 + ((lane>>4)<<3) + jj;
    int n = lane & 15;
    vf[idx] = (h < 798 && n < 12) ? (ushort_t)f2b(vw[h*12 + n]) : (ushort_t)0;
  } else if (bx < 706) {                 // ner = embed@linear_w + b (one wave per row)
    float* ner = (float*)(ws + WS_NER);
    int w = tid >> 6, lane = tid & 63;
    int row = (bx-450)*4 + w;            // < 1024
    float acc[9];
    #pragma unroll
    for (int i=0;i<9;i++) acc[i]=0.f;
    const float* erow = embed + row*768;
    for (int kk=0; kk<12; kk++) {
      int k = kk*64 + lane;
      float e = erow[k];
      #pragma unroll
      for (int i=0;i<9;i++) acc[i] = __builtin_fmaf(e, lw[k*9+i], acc[i]);
    }
    #pragma unroll
    for (int i=0;i<9;i++) {
      float v = acc[i];
      for (int off=32; off>0; off>>=1) v += __shfl_down(v, off);
      if (lane == 0) ner[row*9+i] = v + lb[i];
    }
  } else if (bx < 763) {                 // lab2[g][n] = exp2(C2 * label_emb[g]@[U|W][768:798,n])
    float* lab2 = (float*)(ws + WS_LAB2);
    int idx = (bx-706)*256 + tid;
    if (idx < 14400) {
      int g = idx / 1600, n = idx - g*1600;
      const float* X = (n < 800) ? uw : ww;
      int nn = (n < 800) ? n : (n - 800);
      float v = 1.0f;                    // pad columns: multiplicative identity
      if (nn < 798) {
        float s = 0.f;
        for (int l=0;l<30;l++)
          s = __builtin_fmaf(lemb[g*30+l], X[(768+l)*798 + nn], s);
        v = __builtin_amdgcn_exp2f(s * C2F);
      }
      lab2[idx] = v;
    }
  } else {                               // csum[r] = sum_h V[h,r]
    float* csum = (float*)(ws + WS_CSUM);
    if (tid < 12) {
      float s = 0.f;
      for (int h=0;h<798;h++) s += vw[h*12 + tid];
      csum[tid] = s;
    }
  }
}

// ---------------------------------------------------- K2: Viterbi (1 block)
__global__ __launch_bounds__(256) void viterbi_kernel(
    const float* __restrict__ start_t, const float* __restrict__ trans,
    const float* __restrict__ end_t,
    char* __restrict__ ws, float* __restrict__ out_tags)
{
  __shared__ char smem[46848];
  float* scores = (float*)smem;                    // [4][256][9] f32, 36864 B
  u64* pk = (u64*)(smem + 36864);                  // [4][256] packed funcs
  float* trl = (float*)(smem + 45056);             // [81]
  int* lastArr = (int*)(smem + 45384);             // [4]
  unsigned char* tagbuf = (unsigned char*)(smem + 45400);  // [4][256]
  const float* ner = (const float*)(ws + WS_NER);
  int* tags = (int*)(ws + WS_TAGS);
  int tid = threadIdx.x;
  int w = tid>>6, lane = tid&63;
  int b = w;
  int tt = lane < 9 ? lane : 8;
  if (tid < 81) trl[tid] = trans[tid];

  float tcol[9];
  #pragma unroll
  for (int p=0;p<9;p++) tcol[p] = trans[p*9+tt];
  const float* nb = ner + (b*256)*9 + tt;
  float score = start_t[tt] + nb[0];
  if (lane < 9) scores[(b*256 + 0)*9 + tt] = score;

  float cur[15], nxt[15];
  #pragma unroll
  for (int j=0;j<15;j++) cur[j] = nb[(1+j)*9];
  #define RL(p) (__uint_as_float(__builtin_amdgcn_readlane(__float_as_uint(score), p)) + tcol[p])
  for (int ch=0; ch<17; ch++) {
    int sb = 1 + ch*15;
    if (ch < 16) {
      #pragma unroll
      for (int j=0;j<15;j++) nxt[j] = nb[(sb+15+j)*9];
    }
    #pragma unroll
    for (int j=0;j<15;j++) {
      float m0 = fmaxf(fmaxf(RL(0),RL(1)),RL(2));
      float m1 = fmaxf(fmaxf(RL(3),RL(4)),RL(5));
      float m2 = fmaxf(fmaxf(RL(6),RL(7)),RL(8));
      score = fmaxf(fmaxf(m0,m1),m2) + cur[j];
      if (lane < 9) scores[(b*256 + sb + j)*9 + tt] = score;
    }
    #pragma unroll
    for (int j=0;j<15;j++) cur[j] = nxt[j];
  }
  {
    float fin = score + end_t[tt];
    #define RLF(p) __uint_as_float(__builtin_amdgcn_readlane(__float_as_uint(fin), p))
    float bv = RLF(0); int ba = 0;
    #pragma unroll
    for (int p=1;p<9;p++) { float v = RLF(p); if (v > bv) { bv = v; ba = p; } }
    if (lane == 0) lastArr[b] = ba;
    #undef RLF
  }
  #undef RL
  __syncthreads();

  for (int idx = tid; idx < 1024; idx += 256) {
    int bb = idx >> 8, s = idx & 255;
    u64 f;
    if (s == 255) f = 0x876543210ULL;              // identity
    else {
      const float* srow = &scores[(bb*256 + s)*9];
      float sp[9];
      #pragma unroll
      for (int p=0;p<9;p++) sp[p] = srow[p];
      f = 0;
      #pragma unroll
      for (int t=0;t<9;t++) {
        float best = sp[0] + trl[t]; int arg = 0;
        #pragma unroll
        for (int p=1;p<9;p++) {
          float v = sp[p] + trl[p*9 + t];
          if (v > best) { best = v; arg = p; }
        }
        f |= (u64)arg << (4*t);
      }
    }
    pk[bb*256 + s] = f;
  }
  __syncthreads();

  if (tid < 64) {
    int cb = tid >> 4, c = tid & 15;
    u64 fs[16];
    #pragma unroll
    for (int j=0;j<16;j++) fs[j] = pk[cb*256 + c*16 + j];
    u64 G = fs[15];
    #pragma unroll
    for (int j=14;j>=0;j--) G = fcompose(fs[j], G);
    u64 F = G;
    #pragma unroll
    for (int d=1; d<16; d<<=1) {
      u64 H = __shfl(F, tid + d);
      if (c + d < 16) F = fcompose(F, H);
    }
    int last = lastArr[cb];
    u64 Hn = __shfl(F, (c==15) ? tid : tid+1);
    unsigned t_cur = (c==15) ? (unsigned)last
                             : (unsigned)((Hn >> (4*last)) & 15u);
    #pragma unroll
    for (int j=15;j>=0;j--) {
      t_cur = (unsigned)((fs[j] >> (4*t_cur)) & 15u);
      tagbuf[cb*256 + c*16 + j] = (unsigned char)t_cur;
    }
  }
  __syncthreads();

  for (int idx = tid; idx < 1024; idx += 256) {
    int tg = (int)tagbuf[idx];
    tags[idx] = tg;
    out_tags[idx] = (float)tg;
  }
}

// --------------------------------------------------------------- scorer ----
// scores = csum[r] - 2*sum_h r*V[h,r], r = 1/(Eu*Ew + 1) via magic+1NR
__device__ __forceinline__ unsigned rpair(int uvw, int wvw){
  f32x2 xu; xu.x = lo16(uvw); xu.y = hi16g(uvw);
  f32x2 xw; xw.x = lo16(wvw); xw.y = hi16g(wvw);
  f32x2 p = xu * xw;                               // v_pk_mul_f32
  p = p + (f32x2){1.0f, 1.0f};                     // v_pk_add_f32
  // fast reciprocal: y0 = magic - bits(x); y1 = y0*(2 - x*y0)  (~0.4% rel)
  f32x2 y;
  y.x = __uint_as_float(0x7EF311C3u - __float_as_uint(p.x));
  y.y = __uint_as_float(0x7EF311C3u - __float_as_uint(p.y));
  f32x2 t = (f32x2){2.0f, 2.0f} - p*y;             // v_pk_fma_f32
  y = y * t;                                       // v_pk_mul_f32
  return pkbf16(y.y, y.x);
}

__global__ __launch_bounds__(256) void scorer_kernel(
    char* __restrict__ ws, const int* __restrict__ none_p,
    float* __restrict__ d_out)
{
  __shared__ ushort_t su[8][804];
  __shared__ ushort_t sw[16][804];
  const ushort_t* uw2 = (const ushort_t*)(ws + WS_UW2);
  const float* lab2   = (const float*)(ws + WS_LAB2);
  const ushort_t* vf  = (const ushort_t*)(ws + WS_VFRAG);
  const int* tags     = (const int*)(ws + WS_TAGS);
  const float* csum   = (const float*)(ws + WS_CSUM);
  float* out_sc = d_out + 1024;
  int bx = blockIdx.x, tid = threadIdx.x;
  int b = bx >> 9, ti = (bx>>4)&31, tj = bx&15;
  int I0 = ti*8, J0 = tj*16, bS = b*256;

  for (int idx = tid; idx < 800; idx += 256) {    // stage su = Eu * Elab[tag] (bf16)
    int row = idx / 100, c8 = idx - row*100, kc = c8*8;
    int grow = bS + I0 + row;
    int tag = tags[grow];
    i32x4 uv = *(const i32x4*)(uw2 + (size_t)grow*1600 + kc);
    const float* lp = lab2 + tag*1600 + kc;
    f32x4 l0 = *(const f32x4*)lp;
    f32x4 l1 = *(const f32x4*)(lp+4);
    i32x4 q = (i32x4){ (int)pkbf16(hi16g(uv.x)*l0.y, lo16(uv.x)*l0.x),
                       (int)pkbf16(hi16g(uv.y)*l0.w, lo16(uv.y)*l0.z),
                       (int)pkbf16(hi16g(uv.z)*l1.y, lo16(uv.z)*l1.x),
                       (int)pkbf16(hi16g(uv.w)*l1.w, lo16(uv.w)*l1.z) };
    *(i32x4*)&su[row][kc] = q;
  }
  for (int idx = tid; idx < 1600; idx += 256) {   // stage sw = Ew * Elab[tag] (bf16)
    int row = idx / 100, c8 = idx - row*100, kc = c8*8;
    int grow = bS + J0 + row;
    int tag = tags[grow];
    i32x4 uv = *(const i32x4*)(uw2 + (size_t)grow*1600 + 800 + kc);
    const float* lp = lab2 + tag*1600 + 800 + kc;
    f32x4 l0 = *(const f32x4*)lp;
    f32x4 l1 = *(const f32x4*)(lp+4);
    i32x4 q = (i32x4){ (int)pkbf16(hi16g(uv.x)*l0.y, lo16(uv.x)*l0.x),
                       (int)pkbf16(hi16g(uv.y)*l0.w, lo16(uv.y)*l0.z),
                       (int)pkbf16(hi16g(uv.z)*l1.y, lo16(uv.z)*l1.x),
                       (int)pkbf16(hi16g(uv.w)*l1.w, lo16(uv.w)*l1.z) };
    *(i32x4*)&sw[row][kc] = q;
  }
  __syncthreads();

  int lane = tid & 63, w = tid >> 6;
  int m16 = lane & 15, quad = lane >> 4;
  int none = *none_p;

  f32x4 acc[2];
  acc[0] = (f32x4){0.f,0.f,0.f,0.f};
  acc[1] = (f32x4){0.f,0.f,0.f,0.f};

  const ushort_t* vlane = vf + lane*8;
  i32x4 bfc = *(const i32x4*)vlane;
  for (int c=0; c<25; c++) {
    i32x4 bfn;
    if (c < 24) bfn = *(const i32x4*)(vlane + (c+1)*512);
    int koff = c*32 + quad*8;
    i32x4 wv = *(const i32x4*)&sw[m16][koff];
    bf16x8 bfrag = __builtin_bit_cast(bf16x8, bfc);
    #pragma unroll
    for (int it=0; it<2; it++) {
      i32x4 uv = *(const i32x4*)&su[w*2+it][koff];
      unsigned a0 = rpair(uv.x, wv.x);
      unsigned a1 = rpair(uv.y, wv.y);
      unsigned a2 = rpair(uv.z, wv.z);
      unsigned a3 = rpair(uv.w, wv.w);
      i32x4 avv = (i32x4){(int)a0,(int)a1,(int)a2,(int)a3};
      bf16x8 af = __builtin_bit_cast(bf16x8, avv);
      acc[it] = __builtin_amdgcn_mfma_f32_16x16x32_bf16(af, bfrag, acc[it], 0,0,0);
    }
    bfc = bfn;
  }

  int r = m16;                         // D: col=lane&15 -> r, row=quad*4+reg -> j_local
  if (r < 12) {
    float cs = csum[r];
    #pragma unroll
    for (int it=0; it<2; it++) {
      int gi = I0 + w*2 + it;
      #pragma unroll
      for (int reg=0; reg<4; reg++) {
        int gj = J0 + quad*4 + reg;
        float v = __builtin_fmaf(-2.0f, acc[it][reg], cs);
        if (gi == gj && r == none) v = 100.0f;
        out_sc[(size_t)((bS + gi)*256 + gj)*12 + r] = v;
      }
    }
  }
}

extern "C" void kernel_launch(void* const* d_in, const int* in_sizes, int n_in,
                              void* d_out, int out_size, void* d_ws, size_t ws_size,
                              hipStream_t stream)
{
  const float* embed = (const float*)d_in[0];
  const float* lw    = (const float*)d_in[1];
  const float* lb    = (const float*)d_in[2];
  const float* st    = (const float*)d_in[3];
  const float* tr    = (const float*)d_in[4];
  const float* et    = (const float*)d_in[5];
  const float* lemb  = (const float*)d_in[6];
  const float* uw    = (const float*)d_in[7];
  const float* ub    = (const float*)d_in[8];
  const float* ww    = (const float*)d_in[9];
  const float* wb    = (const float*)d_in[10];
  const float* vw    = (const float*)d_in[11];
  const int* none_p  = (const int*)d_in[12];
  char* ws = (char*)d_ws;
  float* out = (float*)d_out;

  hipLaunchKernelGGL(gemm_prep_kernel, dim3(764), dim3(256), 0, stream,
                     embed, lw, lb, lemb, uw, ub, ww, wb, vw, ws);
  hipLaunchKernelGGL(viterbi_kernel, dim3(1), dim3(256), 0, stream,
                     st, tr, et, ws, out);
  hipLaunchKernelGGL(scorer_kernel, dim3(2048), dim3(256), 0, stream,
                     ws, none_p, out);
}

// Round 13
// 170.599 us; speedup vs baseline: 1.4487x; 1.0531x over previous
//
#include <hip/hip_runtime.h>

// BERT joint NER+relation head on MI355X (gfx950).
// Inputs: fp32. Output: fp32 flat [tags(1024) | scores(3145728)].
// R13: force-packed scorer math - v_pk_fma_f32 (asm) for P=Eu*Ew+1, then
// single v_pk_sub_u16 magic reciprocal in bf16-bit domain (no NR).
// Exp-product domain (R11), csum epilogue (R10), Viterbi scan (R9).

typedef unsigned short ushort_t;
typedef __attribute__((ext_vector_type(8))) short bf16x8;
typedef __attribute__((ext_vector_type(4))) float f32x4;
typedef __attribute__((ext_vector_type(2))) float f32x2;
typedef __attribute__((ext_vector_type(4))) int i32x4;
typedef unsigned long long u64;

#define C2F 2.8853900817779268f  // 2*log2(e)

// workspace offsets (bytes), all 16-aligned; total 3,401,024 B
#define WS_UW2   0u         // ushort [1024][1600] : bf16( exp2(C2*(embed@[U|W]+bias)) )
#define WS_NER   3276800u   // float  [1024][9]
#define WS_VFRAG 3313664u   // ushort [25][64][8]  : V as 16x16x32 B-fragments (bf16)
#define WS_LAB2  3339264u   // float  [9][1600]    : exp2(C2*(label_emb@[U|W][768:]))
#define WS_TAGS  3396864u   // int    [1024]
#define WS_CSUM  3400960u   // float  [12]         : colsum_r = sum_h V[h,r]

__device__ __forceinline__ unsigned f2b(float f){          // RNE, finite only
  unsigned u = __float_as_uint(f);
  return (u + 0x7FFFu + ((u>>16)&1u)) >> 16;
}
__device__ __forceinline__ unsigned pkbf16(float hi, float lo){
  return __builtin_amdgcn_perm(__float_as_uint(hi), __float_as_uint(lo), 0x07060302u);
}
__device__ __forceinline__ float lo16(int v){ return __uint_as_float(((unsigned)v)<<16); }
__device__ __forceinline__ float hi16(int v){ return __uint_as_float(((unsigned)v)&0xFFFF0000u); }
// hi half WITHOUT masking low bits: rel err < 2^-8 ~ bf16 noise (validated R8/R10)
__device__ __forceinline__ float hi16g(int v){ return __uint_as_float((unsigned)v); }
// compose packed tag-functions (9 nibbles): R[t] = F[H[t]]
__device__ __forceinline__ u64 fcompose(u64 F, u64 H){
  u64 R = 0;
  #pragma unroll
  for (int t=0;t<9;t++){
    unsigned h = (unsigned)(H >> (4*t)) & 15u;
    unsigned v = (unsigned)(F >> (4*h)) & 15u;
    R |= (u64)v << (4*t);
  }
  return R;
}

// ---------------------------------------- K1: GEMM + prep (764 blocks) ----
// [0,400): GEMM; [400,450): V frags; [450,706): ner; [706,763): lab2; 763: csum
__global__ __launch_bounds__(256) void gemm_prep_kernel(
    const float* __restrict__ embed, const float* __restrict__ lw,
    const float* __restrict__ lb,    const float* __restrict__ lemb,
    const float* __restrict__ uw,    const float* __restrict__ ub,
    const float* __restrict__ ww,    const float* __restrict__ wb,
    const float* __restrict__ vw,    char* __restrict__ ws)
{
  __shared__ char smem[10496];
  int bx = blockIdx.x, tid = threadIdx.x;
  if (bx < 400) {
    ushort_t (*As)[40] = (ushort_t(*)[40])smem;            // [m][k] +8 pad
    ushort_t (*Bs)[42] = (ushort_t(*)[42])(smem + 5120);   // [n][k] +10 pad
    ushort_t* uw2 = (ushort_t*)(ws + WS_UW2);
    int bm = bx & 15, bn = bx >> 4;
    int M0 = bm*64, N0 = bn*64;
    int w = tid>>6, lane = tid&63;
    int wr = w>>1, wc = w&1;
    int m16 = lane&15, quad = lane>>4;
    int nl = tid>>2, k8 = (tid&3)<<3;
    int bnn = tid & 63, bw = tid >> 6;
    int gn = N0 + bnn;
    const float* bsrc = uw; int bcol = 0; bool bzero = true;
    if (gn < 798)                    { bsrc = uw; bcol = gn;     bzero = false; }
    else if (gn >= 800 && gn < 1598) { bsrc = ww; bcol = gn-800; bzero = false; }

    f32x4 acc[2][2];
    #pragma unroll
    for (int mi=0;mi<2;mi++)
      #pragma unroll
      for (int ni=0;ni<2;ni++) acc[mi][ni] = (f32x4){0.f,0.f,0.f,0.f};

    f32x4 a_lo, a_hi; float bvals[8];
    {
      const float* ap = &embed[(M0+nl)*768 + k8];
      a_lo = *(const f32x4*)ap; a_hi = *(const f32x4*)(ap+4);
      #pragma unroll
      for (int r=0;r<4;r++) {
        int kk = r*8 + bw*2;
        bvals[2*r]   = bzero ? 0.f : bsrc[(kk  )*798 + bcol];
        bvals[2*r+1] = bzero ? 0.f : bsrc[(kk+1)*798 + bcol];
      }
    }
    for (int k0=0; k0<768; k0+=32) {
      i32x4 av = (i32x4){ (int)pkbf16(a_lo.y,a_lo.x), (int)pkbf16(a_lo.w,a_lo.z),
                          (int)pkbf16(a_hi.y,a_hi.x), (int)pkbf16(a_hi.w,a_hi.z) };
      *(i32x4*)&As[nl][k8] = av;
      #pragma unroll
      for (int r=0;r<4;r++) {
        int kk = r*8 + bw*2;
        *(unsigned*)&Bs[bnn][kk] = pkbf16(bvals[2*r+1], bvals[2*r]);
      }
      __syncthreads();
      if (k0 + 32 < 768) {
        const float* ap = &embed[(M0+nl)*768 + k0 + 32 + k8];
        a_lo = *(const f32x4*)ap; a_hi = *(const f32x4*)(ap+4);
        #pragma unroll
        for (int r=0;r<4;r++) {
          int kk = r*8 + bw*2;
          bvals[2*r]   = bzero ? 0.f : bsrc[(k0+32+kk  )*798 + bcol];
          bvals[2*r+1] = bzero ? 0.f : bsrc[(k0+32+kk+1)*798 + bcol];
        }
      }
      bf16x8 a0 = *(const bf16x8*)&As[wr*32      + m16][quad*8];
      bf16x8 a1 = *(const bf16x8*)&As[wr*32 + 16 + m16][quad*8];
      bf16x8 b0 = *(const bf16x8*)&Bs[wc*32      + m16][quad*8];
      bf16x8 b1 = *(const bf16x8*)&Bs[wc*32 + 16 + m16][quad*8];
      acc[0][0] = __builtin_amdgcn_mfma_f32_16x16x32_bf16(a0,b0,acc[0][0],0,0,0);
      acc[0][1] = __builtin_amdgcn_mfma_f32_16x16x32_bf16(a0,b1,acc[0][1],0,0,0);
      acc[1][0] = __builtin_amdgcn_mfma_f32_16x16x32_bf16(a1,b0,acc[1][0],0,0,0);
      acc[1][1] = __builtin_amdgcn_mfma_f32_16x16x32_bf16(a1,b1,acc[1][1],0,0,0);
      __syncthreads();
    }
    #pragma unroll
    for (int mi=0;mi<2;mi++)
      #pragma unroll
      for (int ni=0;ni<2;ni++)
        #pragma unroll
        for (int reg=0;reg<4;reg++) {
          int gm = M0 + wr*32 + mi*16 + quad*4 + reg;
          int go = N0 + wc*32 + ni*16 + m16;
          float bias = 0.f;
          if (go < 798) bias = ub[go];
          else if (go >= 800 && go < 1598) bias = wb[go-800];
          float v = (acc[mi][ni][reg] + bias) * C2F;
          uw2[gm*1600 + go] = (ushort_t)f2b(__builtin_amdgcn_exp2f(v));
        }
  } else if (bx < 450) {                 // V B-fragments
    ushort_t* vf = (ushort_t*)(ws + WS_VFRAG);
    int idx = (bx-400)*256 + tid;        // < 12800
    int jj = idx & 7, lane = (idx>>3) & 63, c = idx >> 9;
    int h = c*32 + ((lane>>4)<<3) + jj;
    int n = lane & 15;
    vf[idx] = (h < 798 && n < 12) ? (ushort_t)f2b(vw[h*12 + n]) : (ushort_t)0;
  } else if (bx < 706) {                 // ner = embed@linear_w + b (one wave per row)
    float* ner = (float*)(ws + WS_NER);
    int w = tid >> 6, lane = tid & 63;
    int row = (bx-450)*4 + w;            // < 1024
    float acc[9];
    #pragma unroll
    for (int i=0;i<9;i++) acc[i]=0.f;
    const float* erow = embed + row*768;
    for (int kk=0; kk<12; kk++) {
      int k = kk*64 + lane;
      float e = erow[k];
      #pragma unroll
      for (int i=0;i<9;i++) acc[i] = __builtin_fmaf(e, lw[k*9+i], acc[i]);
    }
    #pragma unroll
    for (int i=0;i<9;i++) {
      float v = acc[i];
      for (int off=32; off>0; off>>=1) v += __shfl_down(v, off);
      if (lane == 0) ner[row*9+i] = v + lb[i];
    }
  } else if (bx < 763) {                 // lab2[g][n] = exp2(C2 * label_emb[g]@[U|W][768:798,n])
    float* lab2 = (float*)(ws + WS_LAB2);
    int idx = (bx-706)*256 + tid;
    if (idx < 14400) {
      int g = idx / 1600, n = idx - g*1600;
      const float* X = (n < 800) ? uw : ww;
      int nn = (n < 800) ? n : (n - 800);
      float v = 1.0f;                    // pad columns: multiplicative identity
      if (nn < 798) {
        float s = 0.f;
        for (int l=0;l<30;l++)
          s = __builtin_fmaf(lemb[g*30+l], X[(768+l)*798 + nn], s);
        v = __builtin_amdgcn_exp2f(s * C2F);
      }
      lab2[idx] = v;
    }
  } else {                               // csum[r] = sum_h V[h,r]
    float* csum = (float*)(ws + WS_CSUM);
    if (tid < 12) {
      float s = 0.f;
      for (int h=0;h<798;h++) s += vw[h*12 + tid];
      csum[tid] = s;
    }
  }
}

// ---------------------------------------------------- K2: Viterbi (1 block)
__global__ __launch_bounds__(256) void viterbi_kernel(
    const float* __restrict__ start_t, const float* __restrict__ trans,
    const float* __restrict__ end_t,
    char* __restrict__ ws, float* __restrict__ out_tags)
{
  __shared__ char smem[46848];
  float* scores = (float*)smem;                    // [4][256][9] f32, 36864 B
  u64* pk = (u64*)(smem + 36864);                  // [4][256] packed funcs
  float* trl = (float*)(smem + 45056);             // [81]
  int* lastArr = (int*)(smem + 45384);             // [4]
  unsigned char* tagbuf = (unsigned char*)(smem + 45400);  // [4][256]
  const float* ner = (const float*)(ws + WS_NER);
  int* tags = (int*)(ws + WS_TAGS);
  int tid = threadIdx.x;
  int w = tid>>6, lane = tid&63;
  int b = w;
  int tt = lane < 9 ? lane : 8;
  if (tid < 81) trl[tid] = trans[tid];

  float tcol[9];
  #pragma unroll
  for (int p=0;p<9;p++) tcol[p] = trans[p*9+tt];
  const float* nb = ner + (b*256)*9 + tt;
  float score = start_t[tt] + nb[0];
  if (lane < 9) scores[(b*256 + 0)*9 + tt] = score;

  float cur[15], nxt[15];
  #pragma unroll
  for (int j=0;j<15;j++) cur[j] = nb[(1+j)*9];
  #define RL(p) (__uint_as_float(__builtin_amdgcn_readlane(__float_as_uint(score), p)) + tcol[p])
  for (int ch=0; ch<17; ch++) {
    int sb = 1 + ch*15;
    if (ch < 16) {
      #pragma unroll
      for (int j=0;j<15;j++) nxt[j] = nb[(sb+15+j)*9];
    }
    #pragma unroll
    for (int j=0;j<15;j++) {
      float m0 = fmaxf(fmaxf(RL(0),RL(1)),RL(2));
      float m1 = fmaxf(fmaxf(RL(3),RL(4)),RL(5));
      float m2 = fmaxf(fmaxf(RL(6),RL(7)),RL(8));
      score = fmaxf(fmaxf(m0,m1),m2) + cur[j];
      if (lane < 9) scores[(b*256 + sb + j)*9 + tt] = score;
    }
    #pragma unroll
    for (int j=0;j<15;j++) cur[j] = nxt[j];
  }
  {
    float fin = score + end_t[tt];
    #define RLF(p) __uint_as_float(__builtin_amdgcn_readlane(__float_as_uint(fin), p))
    float bv = RLF(0); int ba = 0;
    #pragma unroll
    for (int p=1;p<9;p++) { float v = RLF(p); if (v > bv) { bv = v; ba = p; } }
    if (lane == 0) lastArr[b] = ba;
    #undef RLF
  }
  #undef RL
  __syncthreads();

  for (int idx = tid; idx < 1024; idx += 256) {
    int bb = idx >> 8, s = idx & 255;
    u64 f;
    if (s == 255) f = 0x876543210ULL;              // identity
    else {
      const float* srow = &scores[(bb*256 + s)*9];
      float sp[9];
      #pragma unroll
      for (int p=0;p<9;p++) sp[p] = srow[p];
      f = 0;
      #pragma unroll
      for (int t=0;t<9;t++) {
        float best = sp[0] + trl[t]; int arg = 0;
        #pragma unroll
        for (int p=1;p<9;p++) {
          float v = sp[p] + trl[p*9 + t];
          if (v > best) { best = v; arg = p; }
        }
        f |= (u64)arg << (4*t);
      }
    }
    pk[bb*256 + s] = f;
  }
  __syncthreads();

  if (tid < 64) {
    int cb = tid >> 4, c = tid & 15;
    u64 fs[16];
    #pragma unroll
    for (int j=0;j<16;j++) fs[j] = pk[cb*256 + c*16 + j];
    u64 G = fs[15];
    #pragma unroll
    for (int j=14;j>=0;j--) G = fcompose(fs[j], G);
    u64 F = G;
    #pragma unroll
    for (int d=1; d<16; d<<=1) {
      u64 H = __shfl(F, tid + d);
      if (c + d < 16) F = fcompose(F, H);
    }
    int last = lastArr[cb];
    u64 Hn = __shfl(F, (c==15) ? tid : tid+1);
    unsigned t_cur = (c==15) ? (unsigned)last
                             : (unsigned)((Hn >> (4*last)) & 15u);
    #pragma unroll
    for (int j=15;j>=0;j--) {
      t_cur = (unsigned)((fs[j] >> (4*t_cur)) & 15u);
      tagbuf[cb*256 + c*16 + j] = (unsigned char)t_cur;
    }
  }
  __syncthreads();

  for (int idx = tid; idx < 1024; idx += 256) {
    int tg = (int)tagbuf[idx];
    tags[idx] = tg;
    out_tags[idx] = (float)tg;
  }
}

// --------------------------------------------------------------- scorer ----
// scores = csum[r] - 2*sum_h r*V[h,r];  r = 1/(Eu*Ew+1) via bf16-domain magic.
// Forced packed math: v_pk_fma_f32 (P+1 both halves), v_pk_sub_u16 (both rcps).
__device__ __forceinline__ unsigned rpair(int uvw, int wvw){
  f32x2 xu; xu.x = lo16(uvw); xu.y = hi16g(uvw);
  f32x2 xw; xw.x = lo16(wvw); xw.y = hi16g(wvw);
  f32x2 one2 = {1.0f, 1.0f};
  f32x2 p;
  asm("v_pk_fma_f32 %0, %1, %2, %3" : "=v"(p) : "v"(xu), "v"(xw), "v"(one2));
  unsigned pb = __builtin_amdgcn_perm(__float_as_uint(p.y), __float_as_uint(p.x), 0x07060302u);
  unsigned magic2 = 0x7EF37EF3u;
  unsigned y;
  asm("v_pk_sub_u16 %0, %1, %2" : "=v"(y) : "v"(magic2), "v"(pb));
  return y;
}

__global__ __launch_bounds__(256) void scorer_kernel(
    char* __restrict__ ws, const int* __restrict__ none_p,
    float* __restrict__ d_out)
{
  __shared__ ushort_t su[8][804];
  __shared__ ushort_t sw[16][804];
  const ushort_t* uw2 = (const ushort_t*)(ws + WS_UW2);
  const float* lab2   = (const float*)(ws + WS_LAB2);
  const ushort_t* vf  = (const ushort_t*)(ws + WS_VFRAG);
  const int* tags     = (const int*)(ws + WS_TAGS);
  const float* csum   = (const float*)(ws + WS_CSUM);
  float* out_sc = d_out + 1024;
  int bx = blockIdx.x, tid = threadIdx.x;
  int b = bx >> 9, ti = (bx>>4)&31, tj = bx&15;
  int I0 = ti*8, J0 = tj*16, bS = b*256;

  for (int idx = tid; idx < 800; idx += 256) {    // stage su = Eu * Elab[tag] (bf16)
    int row = idx / 100, c8 = idx - row*100, kc = c8*8;
    int grow = bS + I0 + row;
    int tag = tags[grow];
    i32x4 uv = *(const i32x4*)(uw2 + (size_t)grow*1600 + kc);
    const float* lp = lab2 + tag*1600 + kc;
    f32x4 l0 = *(const f32x4*)lp;
    f32x4 l1 = *(const f32x4*)(lp+4);
    i32x4 q = (i32x4){ (int)pkbf16(hi16g(uv.x)*l0.y, lo16(uv.x)*l0.x),
                       (int)pkbf16(hi16g(uv.y)*l0.w, lo16(uv.y)*l0.z),
                       (int)pkbf16(hi16g(uv.z)*l1.y, lo16(uv.z)*l1.x),
                       (int)pkbf16(hi16g(uv.w)*l1.w, lo16(uv.w)*l1.z) };
    *(i32x4*)&su[row][kc] = q;
  }
  for (int idx = tid; idx < 1600; idx += 256) {   // stage sw = Ew * Elab[tag] (bf16)
    int row = idx / 100, c8 = idx - row*100, kc = c8*8;
    int grow = bS + J0 + row;
    int tag = tags[grow];
    i32x4 uv = *(const i32x4*)(uw2 + (size_t)grow*1600 + 800 + kc);
    const float* lp = lab2 + tag*1600 + 800 + kc;
    f32x4 l0 = *(const f32x4*)lp;
    f32x4 l1 = *(const f32x4*)(lp+4);
    i32x4 q = (i32x4){ (int)pkbf16(hi16g(uv.x)*l0.y, lo16(uv.x)*l0.x),
                       (int)pkbf16(hi16g(uv.y)*l0.w, lo16(uv.y)*l0.z),
                       (int)pkbf16(hi16g(uv.z)*l1.y, lo16(uv.z)*l1.x),
                       (int)pkbf16(hi16g(uv.w)*l1.w, lo16(uv.w)*l1.z) };
    *(i32x4*)&sw[row][kc] = q;
  }
  __syncthreads();

  int lane = tid & 63, w = tid >> 6;
  int m16 = lane & 15, quad = lane >> 4;
  int none = *none_p;

  f32x4 acc[2];
  acc[0] = (f32x4){0.f,0.f,0.f,0.f};
  acc[1] = (f32x4){0.f,0.f,0.f,0.f};

  const ushort_t* vlane = vf + lane*8;
  i32x4 bfc = *(const i32x4*)vlane;
  for (int c=0; c<25; c++) {
    i32x4 bfn;
    if (c < 24) bfn = *(const i32x4*)(vlane + (c+1)*512);
    int koff = c*32 + quad*8;
    i32x4 wv = *(const i32x4*)&sw[m16][koff];
    bf16x8 bfrag = __builtin_bit_cast(bf16x8, bfc);
    #pragma unroll
    for (int it=0; it<2; it++) {
      i32x4 uv = *(const i32x4*)&su[w*2+it][koff];
      unsigned a0 = rpair(uv.x, wv.x);
      unsigned a1 = rpair(uv.y, wv.y);
      unsigned a2 = rpair(uv.z, wv.z);
      unsigned a3 = rpair(uv.w, wv.w);
      i32x4 avv = (i32x4){(int)a0,(int)a1,(int)a2,(int)a3};
      bf16x8 af = __builtin_bit_cast(bf16x8, avv);
      acc[it] = __builtin_amdgcn_mfma_f32_16x16x32_bf16(af, bfrag, acc[it], 0,0,0);
    }
    bfc = bfn;
  }

  int r = m16;                         // D: col=lane&15 -> r, row=quad*4+reg -> j_local
  if (r < 12) {
    float cs = csum[r];
    #pragma unroll
    for (int it=0; it<2; it++) {
      int gi = I0 + w*2 + it;
      #pragma unroll
      for (int reg=0; reg<4; reg++) {
        int gj = J0 + quad*4 + reg;
        float v = __builtin_fmaf(-2.0f, acc[it][reg], cs);
        if (gi == gj && r == none) v = 100.0f;
        out_sc[(size_t)((bS + gi)*256 + gj)*12 + r] = v;
      }
    }
  }
}

extern "C" void kernel_launch(void* const* d_in, const int* in_sizes, int n_in,
                              void* d_out, int out_size, void* d_ws, size_t ws_size,
                              hipStream_t stream)
{
  const float* embed = (const float*)d_in[0];
  const float* lw    = (const float*)d_in[1];
  const float* lb    = (const float*)d_in[2];
  const float* st    = (const float*)d_in[3];
  const float* tr    = (const float*)d_in[4];
  const float* et    = (const float*)d_in[5];
  const float* lemb  = (const float*)d_in[6];
  const float* uw    = (const float*)d_in[7];
  const float* ub    = (const float*)d_in[8];
  const float* ww    = (const float*)d_in[9];
  const float* wb    = (const float*)d_in[10];
  const float* vw    = (const float*)d_in[11];
  const int* none_p  = (const int*)d_in[12];
  char* ws = (char*)d_ws;
  float* out = (float*)d_out;

  hipLaunchKernelGGL(gemm_prep_kernel, dim3(764), dim3(256), 0, stream,
                     embed, lw, lb, lemb, uw, ub, ww, wb, vw, ws);
  hipLaunchKernelGGL(viterbi_kernel, dim3(1), dim3(256), 0, stream,
                     st, tr, et, ws, out);
  hipLaunchKernelGGL(scorer_kernel, dim3(2048), dim3(256), 0, stream,
                     ws, none_p, out);
}

// Round 14
// 167.136 us; speedup vs baseline: 1.4787x; 1.0207x over previous
//
#include <hip/hip_runtime.h>

// BERT joint NER+relation head on MI355X (gfx950).
// Inputs: fp32. Output: fp32 flat [tags(1024) | scores(3145728)].
// R14: scorer 512-thread blocks (16x16 tile, 24 waves/CU vs 16) - stall-bound
// fix. Packed magic-rcp math (R13), exp-product domain (R11), Viterbi (R9).

typedef unsigned short ushort_t;
typedef __attribute__((ext_vector_type(8))) short bf16x8;
typedef __attribute__((ext_vector_type(4))) float f32x4;
typedef __attribute__((ext_vector_type(2))) float f32x2;
typedef __attribute__((ext_vector_type(4))) int i32x4;
typedef unsigned long long u64;

#define C2F 2.8853900817779268f  // 2*log2(e)

// workspace offsets (bytes), all 16-aligned; total 3,401,024 B
#define WS_UW2   0u         // ushort [1024][1600] : bf16( exp2(C2*(embed@[U|W]+bias)) )
#define WS_NER   3276800u   // float  [1024][9]
#define WS_VFRAG 3313664u   // ushort [25][64][8]  : V as 16x16x32 B-fragments (bf16)
#define WS_LAB2  3339264u   // float  [9][1600]    : exp2(C2*(label_emb@[U|W][768:]))
#define WS_TAGS  3396864u   // int    [1024]
#define WS_CSUM  3400960u   // float  [12]         : colsum_r = sum_h V[h,r]

__device__ __forceinline__ unsigned f2b(float f){          // RNE, finite only
  unsigned u = __float_as_uint(f);
  return (u + 0x7FFFu + ((u>>16)&1u)) >> 16;
}
__device__ __forceinline__ unsigned pkbf16(float hi, float lo){
  return __builtin_amdgcn_perm(__float_as_uint(hi), __float_as_uint(lo), 0x07060302u);
}
__device__ __forceinline__ float lo16(int v){ return __uint_as_float(((unsigned)v)<<16); }
__device__ __forceinline__ float hi16(int v){ return __uint_as_float(((unsigned)v)&0xFFFF0000u); }
// hi half WITHOUT masking low bits: rel err < 2^-8 ~ bf16 noise (validated R8/R10)
__device__ __forceinline__ float hi16g(int v){ return __uint_as_float((unsigned)v); }
// compose packed tag-functions (9 nibbles): R[t] = F[H[t]]
__device__ __forceinline__ u64 fcompose(u64 F, u64 H){
  u64 R = 0;
  #pragma unroll
  for (int t=0;t<9;t++){
    unsigned h = (unsigned)(H >> (4*t)) & 15u;
    unsigned v = (unsigned)(F >> (4*h)) & 15u;
    R |= (u64)v << (4*t);
  }
  return R;
}

// ---------------------------------------- K1: GEMM + prep (764 blocks) ----
// [0,400): GEMM; [400,450): V frags; [450,706): ner; [706,763): lab2; 763: csum
__global__ __launch_bounds__(256) void gemm_prep_kernel(
    const float* __restrict__ embed, const float* __restrict__ lw,
    const float* __restrict__ lb,    const float* __restrict__ lemb,
    const float* __restrict__ uw,    const float* __restrict__ ub,
    const float* __restrict__ ww,    const float* __restrict__ wb,
    const float* __restrict__ vw,    char* __restrict__ ws)
{
  __shared__ char smem[10496];
  int bx = blockIdx.x, tid = threadIdx.x;
  if (bx < 400) {
    ushort_t (*As)[40] = (ushort_t(*)[40])smem;            // [m][k] +8 pad
    ushort_t (*Bs)[42] = (ushort_t(*)[42])(smem + 5120);   // [n][k] +10 pad
    ushort_t* uw2 = (ushort_t*)(ws + WS_UW2);
    int bm = bx & 15, bn = bx >> 4;
    int M0 = bm*64, N0 = bn*64;
    int w = tid>>6, lane = tid&63;
    int wr = w>>1, wc = w&1;
    int m16 = lane&15, quad = lane>>4;
    int nl = tid>>2, k8 = (tid&3)<<3;
    int bnn = tid & 63, bw = tid >> 6;
    int gn = N0 + bnn;
    const float* bsrc = uw; int bcol = 0; bool bzero = true;
    if (gn < 798)                    { bsrc = uw; bcol = gn;     bzero = false; }
    else if (gn >= 800 && gn < 1598) { bsrc = ww; bcol = gn-800; bzero = false; }

    f32x4 acc[2][2];
    #pragma unroll
    for (int mi=0;mi<2;mi++)
      #pragma unroll
      for (int ni=0;ni<2;ni++) acc[mi][ni] = (f32x4){0.f,0.f,0.f,0.f};

    f32x4 a_lo, a_hi; float bvals[8];
    {
      const float* ap = &embed[(M0+nl)*768 + k8];
      a_lo = *(const f32x4*)ap; a_hi = *(const f32x4*)(ap+4);
      #pragma unroll
      for (int r=0;r<4;r++) {
        int kk = r*8 + bw*2;
        bvals[2*r]   = bzero ? 0.f : bsrc[(kk  )*798 + bcol];
        bvals[2*r+1] = bzero ? 0.f : bsrc[(kk+1)*798 + bcol];
      }
    }
    for (int k0=0; k0<768; k0+=32) {
      i32x4 av = (i32x4){ (int)pkbf16(a_lo.y,a_lo.x), (int)pkbf16(a_lo.w,a_lo.z),
                          (int)pkbf16(a_hi.y,a_hi.x), (int)pkbf16(a_hi.w,a_hi.z) };
      *(i32x4*)&As[nl][k8] = av;
      #pragma unroll
      for (int r=0;r<4;r++) {
        int kk = r*8 + bw*2;
        *(unsigned*)&Bs[bnn][kk] = pkbf16(bvals[2*r+1], bvals[2*r]);
      }
      __syncthreads();
      if (k0 + 32 < 768) {
        const float* ap = &embed[(M0+nl)*768 + k0 + 32 + k8];
        a_lo = *(const f32x4*)ap; a_hi = *(const f32x4*)(ap+4);
        #pragma unroll
        for (int r=0;r<4;r++) {
          int kk = r*8 + bw*2;
          bvals[2*r]   = bzero ? 0.f : bsrc[(k0+32+kk  )*798 + bcol];
          bvals[2*r+1] = bzero ? 0.f : bsrc[(k0+32+kk+1)*798 + bcol];
        }
      }
      bf16x8 a0 = *(const bf16x8*)&As[wr*32      + m16][quad*8];
      bf16x8 a1 = *(const bf16x8*)&As[wr*32 + 16 + m16][quad*8];
      bf16x8 b0 = *(const bf16x8*)&Bs[wc*32      + m16][quad*8];
      bf16x8 b1 = *(const bf16x8*)&Bs[wc*32 + 16 + m16][quad*8];
      acc[0][0] = __builtin_amdgcn_mfma_f32_16x16x32_bf16(a0,b0,acc[0][0],0,0,0);
      acc[0][1] = __builtin_amdgcn_mfma_f32_16x16x32_bf16(a0,b1,acc[0][1],0,0,0);
      acc[1][0] = __builtin_amdgcn_mfma_f32_16x16x32_bf16(a1,b0,acc[1][0],0,0,0);
      acc[1][1] = __builtin_amdgcn_mfma_f32_16x16x32_bf16(a1,b1,acc[1][1],0,0,0);
      __syncthreads();
    }
    #pragma unroll
    for (int mi=0;mi<2;mi++)
      #pragma unroll
      for (int ni=0;ni<2;ni++)
        #pragma unroll
        for (int reg=0;reg<4;reg++) {
          int gm = M0 + wr*32 + mi*16 + quad*4 + reg;
          int go = N0 + wc*32 + ni*16 + m16;
          float bias = 0.f;
          if (go < 798) bias = ub[go];
          else if (go >= 800 && go < 1598) bias = wb[go-800];
          float v = (acc[mi][ni][reg] + bias) * C2F;
          uw2[gm*1600 + go] = (ushort_t)f2b(__builtin_amdgcn_exp2f(v));
        }
  } else if (bx < 450) {                 // V B-fragments
    ushort_t* vf = (ushort_t*)(ws + WS_VFRAG);
    int idx = (bx-400)*256 + tid;        // < 12800
    int jj = idx & 7, lane = (idx>>3) & 63, c = idx >> 9;
    int h = c*32 + ((lane>>4)<<3) + jj;
    int n = lane & 15;
    vf[idx] = (h < 798 && n < 12) ? (ushort_t)f2b(vw[h*12 + n]) : (ushort_t)0;
  } else if (bx < 706) {                 // ner = embed@linear_w + b (one wave per row)
    float* ner = (float*)(ws + WS_NER);
    int w = tid >> 6, lane = tid & 63;
    int row = (bx-450)*4 + w;            // < 1024
    float acc[9];
    #pragma unroll
    for (int i=0;i<9;i++) acc[i]=0.f;
    const float* erow = embed + row*768;
    for (int kk=0; kk<12; kk++) {
      int k = kk*64 + lane;
      float e = erow[k];
      #pragma unroll
      for (int i=0;i<9;i++) acc[i] = __builtin_fmaf(e, lw[k*9+i], acc[i]);
    }
    #pragma unroll
    for (int i=0;i<9;i++) {
      float v = acc[i];
      for (int off=32; off>0; off>>=1) v += __shfl_down(v, off);
      if (lane == 0) ner[row*9+i] = v + lb[i];
    }
  } else if (bx < 763) {                 // lab2[g][n] = exp2(C2 * label_emb[g]@[U|W][768:798,n])
    float* lab2 = (float*)(ws + WS_LAB2);
    int idx = (bx-706)*256 + tid;
    if (idx < 14400) {
      int g = idx / 1600, n = idx - g*1600;
      const float* X = (n < 800) ? uw : ww;
      int nn = (n < 800) ? n : (n - 800);
      float v = 1.0f;                    // pad columns: multiplicative identity
      if (nn < 798) {
        float s = 0.f;
        for (int l=0;l<30;l++)
          s = __builtin_fmaf(lemb[g*30+l], X[(768+l)*798 + nn], s);
        v = __builtin_amdgcn_exp2f(s * C2F);
      }
      lab2[idx] = v;
    }
  } else {                               // csum[r] = sum_h V[h,r]
    float* csum = (float*)(ws + WS_CSUM);
    if (tid < 12) {
      float s = 0.f;
      for (int h=0;h<798;h++) s += vw[h*12 + tid];
      csum[tid] = s;
    }
  }
}

// ---------------------------------------------------- K2: Viterbi (1 block)
__global__ __launch_bounds__(256) void viterbi_kernel(
    const float* __restrict__ start_t, const float* __restrict__ trans,
    const float* __restrict__ end_t,
    char* __restrict__ ws, float* __restrict__ out_tags)
{
  __shared__ char smem[46848];
  float* scores = (float*)smem;                    // [4][256][9] f32, 36864 B
  u64* pk = (u64*)(smem + 36864);                  // [4][256] packed funcs
  float* trl = (float*)(smem + 45056);             // [81]
  int* lastArr = (int*)(smem + 45384);             // [4]
  unsigned char* tagbuf = (unsigned char*)(smem + 45400);  // [4][256]
  const float* ner = (const float*)(ws + WS_NER);
  int* tags = (int*)(ws + WS_TAGS);
  int tid = threadIdx.x;
  int w = tid>>6, lane = tid&63;
  int b = w;
  int tt = lane < 9 ? lane : 8;
  if (tid < 81) trl[tid] = trans[tid];

  float tcol[9];
  #pragma unroll
  for (int p=0;p<9;p++) tcol[p] = trans[p*9+tt];
  const float* nb = ner + (b*256)*9 + tt;
  float score = start_t[tt] + nb[0];
  if (lane < 9) scores[(b*256 + 0)*9 + tt] = score;

  float cur[15], nxt[15];
  #pragma unroll
  for (int j=0;j<15;j++) cur[j] = nb[(1+j)*9];
  #define RL(p) (__uint_as_float(__builtin_amdgcn_readlane(__float_as_uint(score), p)) + tcol[p])
  for (int ch=0; ch<17; ch++) {
    int sb = 1 + ch*15;
    if (ch < 16) {
      #pragma unroll
      for (int j=0;j<15;j++) nxt[j] = nb[(sb+15+j)*9];
    }
    #pragma unroll
    for (int j=0;j<15;j++) {
      float m0 = fmaxf(fmaxf(RL(0),RL(1)),RL(2));
      float m1 = fmaxf(fmaxf(RL(3),RL(4)),RL(5));
      float m2 = fmaxf(fmaxf(RL(6),RL(7)),RL(8));
      score = fmaxf(fmaxf(m0,m1),m2) + cur[j];
      if (lane < 9) scores[(b*256 + sb + j)*9 + tt] = score;
    }
    #pragma unroll
    for (int j=0;j<15;j++) cur[j] = nxt[j];
  }
  {
    float fin = score + end_t[tt];
    #define RLF(p) __uint_as_float(__builtin_amdgcn_readlane(__float_as_uint(fin), p))
    float bv = RLF(0); int ba = 0;
    #pragma unroll
    for (int p=1;p<9;p++) { float v = RLF(p); if (v > bv) { bv = v; ba = p; } }
    if (lane == 0) lastArr[b] = ba;
    #undef RLF
  }
  #undef RL
  __syncthreads();

  for (int idx = tid; idx < 1024; idx += 256) {
    int bb = idx >> 8, s = idx & 255;
    u64 f;
    if (s == 255) f = 0x876543210ULL;              // identity
    else {
      const float* srow = &scores[(bb*256 + s)*9];
      float sp[9];
      #pragma unroll
      for (int p=0;p<9;p++) sp[p] = srow[p];
      f = 0;
      #pragma unroll
      for (int t=0;t<9;t++) {
        float best = sp[0] + trl[t]; int arg = 0;
        #pragma unroll
        for (int p=1;p<9;p++) {
          float v = sp[p] + trl[p*9 + t];
          if (v > best) { best = v; arg = p; }
        }
        f |= (u64)arg << (4*t);
      }
    }
    pk[bb*256 + s] = f;
  }
  __syncthreads();

  if (tid < 64) {
    int cb = tid >> 4, c = tid & 15;
    u64 fs[16];
    #pragma unroll
    for (int j=0;j<16;j++) fs[j] = pk[cb*256 + c*16 + j];
    u64 G = fs[15];
    #pragma unroll
    for (int j=14;j>=0;j--) G = fcompose(fs[j], G);
    u64 F = G;
    #pragma unroll
    for (int d=1; d<16; d<<=1) {
      u64 H = __shfl(F, tid + d);
      if (c + d < 16) F = fcompose(F, H);
    }
    int last = lastArr[cb];
    u64 Hn = __shfl(F, (c==15) ? tid : tid+1);
    unsigned t_cur = (c==15) ? (unsigned)last
                             : (unsigned)((Hn >> (4*last)) & 15u);
    #pragma unroll
    for (int j=15;j>=0;j--) {
      t_cur = (unsigned)((fs[j] >> (4*t_cur)) & 15u);
      tagbuf[cb*256 + c*16 + j] = (unsigned char)t_cur;
    }
  }
  __syncthreads();

  for (int idx = tid; idx < 1024; idx += 256) {
    int tg = (int)tagbuf[idx];
    tags[idx] = tg;
    out_tags[idx] = (float)tg;
  }
}

// --------------------------------------------------------------- scorer ----
// scores = csum[r] - 2*sum_h r*V[h,r];  r = 1/(Eu*Ew+1) via bf16-domain magic.
// 1024 blocks x 512 threads: 16i x 16j tile, LDS 51.4KB -> 3 blk/CU = 24 waves.
__device__ __forceinline__ unsigned rpair(int uvw, int wvw){
  f32x2 xu; xu.x = lo16(uvw); xu.y = hi16g(uvw);
  f32x2 xw; xw.x = lo16(wvw); xw.y = hi16g(wvw);
  f32x2 one2 = {1.0f, 1.0f};
  f32x2 p;
  asm("v_pk_fma_f32 %0, %1, %2, %3" : "=v"(p) : "v"(xu), "v"(xw), "v"(one2));
  unsigned pb = __builtin_amdgcn_perm(__float_as_uint(p.y), __float_as_uint(p.x), 0x07060302u);
  unsigned magic2 = 0x7EF37EF3u;
  unsigned y;
  asm("v_pk_sub_u16 %0, %1, %2" : "=v"(y) : "v"(magic2), "v"(pb));
  return y;
}

__global__ __launch_bounds__(512) void scorer_kernel(
    char* __restrict__ ws, const int* __restrict__ none_p,
    float* __restrict__ d_out)
{
  __shared__ ushort_t su[16][804];
  __shared__ ushort_t sw[16][804];
  const ushort_t* uw2 = (const ushort_t*)(ws + WS_UW2);
  const float* lab2   = (const float*)(ws + WS_LAB2);
  const ushort_t* vf  = (const ushort_t*)(ws + WS_VFRAG);
  const int* tags     = (const int*)(ws + WS_TAGS);
  const float* csum   = (const float*)(ws + WS_CSUM);
  float* out_sc = d_out + 1024;
  int bx = blockIdx.x, tid = threadIdx.x;
  int b = bx >> 8, ti = (bx>>4)&15, tj = bx&15;
  int I0 = ti*16, J0 = tj*16, bS = b*256;

  for (int idx = tid; idx < 1600; idx += 512) {   // stage su = Eu * Elab[tag] (bf16)
    int row = idx / 100, c8 = idx - row*100, kc = c8*8;
    int grow = bS + I0 + row;
    int tag = tags[grow];
    i32x4 uv = *(const i32x4*)(uw2 + (size_t)grow*1600 + kc);
    const float* lp = lab2 + tag*1600 + kc;
    f32x4 l0 = *(const f32x4*)lp;
    f32x4 l1 = *(const f32x4*)(lp+4);
    i32x4 q = (i32x4){ (int)pkbf16(hi16g(uv.x)*l0.y, lo16(uv.x)*l0.x),
                       (int)pkbf16(hi16g(uv.y)*l0.w, lo16(uv.y)*l0.z),
                       (int)pkbf16(hi16g(uv.z)*l1.y, lo16(uv.z)*l1.x),
                       (int)pkbf16(hi16g(uv.w)*l1.w, lo16(uv.w)*l1.z) };
    *(i32x4*)&su[row][kc] = q;
  }
  for (int idx = tid; idx < 1600; idx += 512) {   // stage sw = Ew * Elab[tag] (bf16)
    int row = idx / 100, c8 = idx - row*100, kc = c8*8;
    int grow = bS + J0 + row;
    int tag = tags[grow];
    i32x4 uv = *(const i32x4*)(uw2 + (size_t)grow*1600 + 800 + kc);
    const float* lp = lab2 + tag*1600 + 800 + kc;
    f32x4 l0 = *(const f32x4*)lp;
    f32x4 l1 = *(const f32x4*)(lp+4);
    i32x4 q = (i32x4){ (int)pkbf16(hi16g(uv.x)*l0.y, lo16(uv.x)*l0.x),
                       (int)pkbf16(hi16g(uv.y)*l0.w, lo16(uv.y)*l0.z),
                       (int)pkbf16(hi16g(uv.z)*l1.y, lo16(uv.z)*l1.x),
                       (int)pkbf16(hi16g(uv.w)*l1.w, lo16(uv.w)*l1.z) };
    *(i32x4*)&sw[row][kc] = q;
  }
  __syncthreads();

  int lane = tid & 63, w = tid >> 6;   // 8 waves
  int m16 = lane & 15, quad = lane >> 4;
  int none = *none_p;

  f32x4 acc[2];
  acc[0] = (f32x4){0.f,0.f,0.f,0.f};
  acc[1] = (f32x4){0.f,0.f,0.f,0.f};

  const ushort_t* vlane = vf + lane*8;
  i32x4 bfc = *(const i32x4*)vlane;
  for (int c=0; c<25; c++) {
    i32x4 bfn;
    if (c < 24) bfn = *(const i32x4*)(vlane + (c+1)*512);
    int koff = c*32 + quad*8;
    i32x4 wv = *(const i32x4*)&sw[m16][koff];
    bf16x8 bfrag = __builtin_bit_cast(bf16x8, bfc);
    #pragma unroll
    for (int it=0; it<2; it++) {
      i32x4 uv = *(const i32x4*)&su[w*2+it][koff];
      unsigned a0 = rpair(uv.x, wv.x);
      unsigned a1 = rpair(uv.y, wv.y);
      unsigned a2 = rpair(uv.z, wv.z);
      unsigned a3 = rpair(uv.w, wv.w);
      i32x4 avv = (i32x4){(int)a0,(int)a1,(int)a2,(int)a3};
      bf16x8 af = __builtin_bit_cast(bf16x8, avv);
      acc[it] = __builtin_amdgcn_mfma_f32_16x16x32_bf16(af, bfrag, acc[it], 0,0,0);
    }
    bfc = bfn;
  }

  int r = m16;                         // D: col=lane&15 -> r, row=quad*4+reg -> j_local
  if (r < 12) {
    float cs = csum[r];
    #pragma unroll
    for (int it=0; it<2; it++) {
      int gi = I0 + w*2 + it;
      #pragma unroll
      for (int reg=0; reg<4; reg++) {
        int gj = J0 + quad*4 + reg;
        float v = __builtin_fmaf(-2.0f, acc[it][reg], cs);
        if (gi == gj && r == none) v = 100.0f;
        out_sc[(size_t)((bS + gi)*256 + gj)*12 + r] = v;
      }
    }
  }
}

extern "C" void kernel_launch(void* const* d_in, const int* in_sizes, int n_in,
                              void* d_out, int out_size, void* d_ws, size_t ws_size,
                              hipStream_t stream)
{
  const float* embed = (const float*)d_in[0];
  const float* lw    = (const float*)d_in[1];
  const float* lb    = (const float*)d_in[2];
  const float* st    = (const float*)d_in[3];
  const float* tr    = (const float*)d_in[4];
  const float* et    = (const float*)d_in[5];
  const float* lemb  = (const float*)d_in[6];
  const float* uw    = (const float*)d_in[7];
  const float* ub    = (const float*)d_in[8];
  const float* ww    = (const float*)d_in[9];
  const float* wb    = (const float*)d_in[10];
  const float* vw    = (const float*)d_in[11];
  const int* none_p  = (const int*)d_in[12];
  char* ws = (char*)d_ws;
  float* out = (float*)d_out;

  hipLaunchKernelGGL(gemm_prep_kernel, dim3(764), dim3(256), 0, stream,
                     embed, lw, lb, lemb, uw, ub, ww, wb, vw, ws);
  hipLaunchKernelGGL(viterbi_kernel, dim3(1), dim3(256), 0, stream,
                     st, tr, et, ws, out);
  hipLaunchKernelGGL(scorer_kernel, dim3(1024), dim3(512), 0, stream,
                     ws, none_p, out);
}

// Round 15
// 166.975 us; speedup vs baseline: 1.4802x; 1.0010x over previous
//
#include <hip/hip_runtime.h>

// BERT joint NER+relation head on MI355X (gfx950).
// Inputs: fp32. Output: fp32 flat [tags(1024) | scores(3145728)].
// R15: fuse_kernel folds Elab[tag] into uw2 in place; scorer drops su-LDS
// (streams A-operand from L2) -> LDS 25.7KB, 4 blk/CU x 512 thr = 32 waves,
// 1024 blocks = one clean round. Packed magic-rcp (R13), exp domain (R11).

typedef unsigned short ushort_t;
typedef __attribute__((ext_vector_type(8))) short bf16x8;
typedef __attribute__((ext_vector_type(4))) float f32x4;
typedef __attribute__((ext_vector_type(2))) float f32x2;
typedef __attribute__((ext_vector_type(4))) int i32x4;
typedef unsigned long long u64;

#define C2F 2.8853900817779268f  // 2*log2(e)

// workspace offsets (bytes), all 16-aligned (ws_size = 256 MiB, plenty)
#define WS_UW2   0u         // ushort [1024][1600] : bf16(exp2(C2*(embed@[U|W]+bias))), lab-fused in place
#define WS_NER   3276800u   // float  [1024][9]
#define WS_VFRAG 3313664u   // ushort [25][64][8]  : V as 16x16x32 B-fragments (bf16)
#define WS_LAB2  3339264u   // float  [9][1600]    : exp2(C2*(label_emb@[U|W][768:]))
#define WS_TAGS  3396864u   // int    [1024]
#define WS_CSUM  3400960u   // float  [12]         : colsum_r = sum_h V[h,r]

__device__ __forceinline__ unsigned f2b(float f){          // RNE, finite only
  unsigned u = __float_as_uint(f);
  return (u + 0x7FFFu + ((u>>16)&1u)) >> 16;
}
__device__ __forceinline__ unsigned pkbf16(float hi, float lo){
  return __builtin_amdgcn_perm(__float_as_uint(hi), __float_as_uint(lo), 0x07060302u);
}
__device__ __forceinline__ float lo16(int v){ return __uint_as_float(((unsigned)v)<<16); }
__device__ __forceinline__ float hi16g(int v){ return __uint_as_float((unsigned)v); }
// compose packed tag-functions (9 nibbles): R[t] = F[H[t]]
__device__ __forceinline__ u64 fcompose(u64 F, u64 H){
  u64 R = 0;
  #pragma unroll
  for (int t=0;t<9;t++){
    unsigned h = (unsigned)(H >> (4*t)) & 15u;
    unsigned v = (unsigned)(F >> (4*h)) & 15u;
    R |= (u64)v << (4*t);
  }
  return R;
}

// ---------------------------------------- K1: GEMM + prep (764 blocks) ----
// [0,400): GEMM; [400,450): V frags; [450,706): ner; [706,763): lab2; 763: csum
__global__ __launch_bounds__(256) void gemm_prep_kernel(
    const float* __restrict__ embed, const float* __restrict__ lw,
    const float* __restrict__ lb,    const float* __restrict__ lemb,
    const float* __restrict__ uw,    const float* __restrict__ ub,
    const float* __restrict__ ww,    const float* __restrict__ wb,
    const float* __restrict__ vw,    char* __restrict__ ws)
{
  __shared__ char smem[10496];
  int bx = blockIdx.x, tid = threadIdx.x;
  if (bx < 400) {
    ushort_t (*As)[40] = (ushort_t(*)[40])smem;            // [m][k] +8 pad
    ushort_t (*Bs)[42] = (ushort_t(*)[42])(smem + 5120);   // [n][k] +10 pad
    ushort_t* uw2 = (ushort_t*)(ws + WS_UW2);
    int bm = bx & 15, bn = bx >> 4;
    int M0 = bm*64, N0 = bn*64;
    int w = tid>>6, lane = tid&63;
    int wr = w>>1, wc = w&1;
    int m16 = lane&15, quad = lane>>4;
    int nl = tid>>2, k8 = (tid&3)<<3;
    int bnn = tid & 63, bw = tid >> 6;
    int gn = N0 + bnn;
    const float* bsrc = uw; int bcol = 0; bool bzero = true;
    if (gn < 798)                    { bsrc = uw; bcol = gn;     bzero = false; }
    else if (gn >= 800 && gn < 1598) { bsrc = ww; bcol = gn-800; bzero = false; }

    f32x4 acc[2][2];
    #pragma unroll
    for (int mi=0;mi<2;mi++)
      #pragma unroll
      for (int ni=0;ni<2;ni++) acc[mi][ni] = (f32x4){0.f,0.f,0.f,0.f};

    f32x4 a_lo, a_hi; float bvals[8];
    {
      const float* ap = &embed[(M0+nl)*768 + k8];
      a_lo = *(const f32x4*)ap; a_hi = *(const f32x4*)(ap+4);
      #pragma unroll
      for (int r=0;r<4;r++) {
        int kk = r*8 + bw*2;
        bvals[2*r]   = bzero ? 0.f : bsrc[(kk  )*798 + bcol];
        bvals[2*r+1] = bzero ? 0.f : bsrc[(kk+1)*798 + bcol];
      }
    }
    for (int k0=0; k0<768; k0+=32) {
      i32x4 av = (i32x4){ (int)pkbf16(a_lo.y,a_lo.x), (int)pkbf16(a_lo.w,a_lo.z),
                          (int)pkbf16(a_hi.y,a_hi.x), (int)pkbf16(a_hi.w,a_hi.z) };
      *(i32x4*)&As[nl][k8] = av;
      #pragma unroll
      for (int r=0;r<4;r++) {
        int kk = r*8 + bw*2;
        *(unsigned*)&Bs[bnn][kk] = pkbf16(bvals[2*r+1], bvals[2*r]);
      }
      __syncthreads();
      if (k0 + 32 < 768) {
        const float* ap = &embed[(M0+nl)*768 + k0 + 32 + k8];
        a_lo = *(const f32x4*)ap; a_hi = *(const f32x4*)(ap+4);
        #pragma unroll
        for (int r=0;r<4;r++) {
          int kk = r*8 + bw*2;
          bvals[2*r]   = bzero ? 0.f : bsrc[(k0+32+kk  )*798 + bcol];
          bvals[2*r+1] = bzero ? 0.f : bsrc[(k0+32+kk+1)*798 + bcol];
        }
      }
      bf16x8 a0 = *(const bf16x8*)&As[wr*32      + m16][quad*8];
      bf16x8 a1 = *(const bf16x8*)&As[wr*32 + 16 + m16][quad*8];
      bf16x8 b0 = *(const bf16x8*)&Bs[wc*32      + m16][quad*8];
      bf16x8 b1 = *(const bf16x8*)&Bs[wc*32 + 16 + m16][quad*8];
      acc[0][0] = __builtin_amdgcn_mfma_f32_16x16x32_bf16(a0,b0,acc[0][0],0,0,0);
      acc[0][1] = __builtin_amdgcn_mfma_f32_16x16x32_bf16(a0,b1,acc[0][1],0,0,0);
      acc[1][0] = __builtin_amdgcn_mfma_f32_16x16x32_bf16(a1,b0,acc[1][0],0,0,0);
      acc[1][1] = __builtin_amdgcn_mfma_f32_16x16x32_bf16(a1,b1,acc[1][1],0,0,0);
      __syncthreads();
    }
    #pragma unroll
    for (int mi=0;mi<2;mi++)
      #pragma unroll
      for (int ni=0;ni<2;ni++)
        #pragma unroll
        for (int reg=0;reg<4;reg++) {
          int gm = M0 + wr*32 + mi*16 + quad*4 + reg;
          int go = N0 + wc*32 + ni*16 + m16;
          float bias = 0.f;
          if (go < 798) bias = ub[go];
          else if (go >= 800 && go < 1598) bias = wb[go-800];
          float v = (acc[mi][ni][reg] + bias) * C2F;
          uw2[gm*1600 + go] = (ushort_t)f2b(__builtin_amdgcn_exp2f(v));
        }
  } else if (bx < 450) {                 // V B-fragments
    ushort_t* vf = (ushort_t*)(ws + WS_VFRAG);
    int idx = (bx-400)*256 + tid;        // < 12800
    int jj = idx & 7, lane = (idx>>3) & 63, c = idx >> 9;
    int h = c*32 + ((lane>>4)<<3) + jj;
    int n = lane & 15;
    vf[idx] = (h < 798 && n < 12) ? (ushort_t)f2b(vw[h*12 + n]) : (ushort_t)0;
  } else if (bx < 706) {                 // ner = embed@linear_w + b (one wave per row)
    float* ner = (float*)(ws + WS_NER);
    int w = tid >> 6, lane = tid & 63;
    int row = (bx-450)*4 + w;            // < 1024
    float acc[9];
    #pragma unroll
    for (int i=0;i<9;i++) acc[i]=0.f;
    const float* erow = embed + row*768;
    for (int kk=0; kk<12; kk++) {
      int k = kk*64 + lane;
      float e = erow[k];
      #pragma unroll
      for (int i=0;i<9;i++) acc[i] = __builtin_fmaf(e, lw[k*9+i], acc[i]);
    }
    #pragma unroll
    for (int i=0;i<9;i++) {
      float v = acc[i];
      for (int off=32; off>0; off>>=1) v += __shfl_down(v, off);
      if (lane == 0) ner[row*9+i] = v + lb[i];
    }
  } else if (bx < 763) {                 // lab2[g][n] = exp2(C2 * label_emb[g]@[U|W][768:798,n])
    float* lab2 = (float*)(ws + WS_LAB2);
    int idx = (bx-706)*256 + tid;
    if (idx < 14400) {
      int g = idx / 1600, n = idx - g*1600;
      const float* X = (n < 800) ? uw : ww;
      int nn = (n < 800) ? n : (n - 800);
      float v = 1.0f;                    // pad columns: multiplicative identity
      if (nn < 798) {
        float s = 0.f;
        for (int l=0;l<30;l++)
          s = __builtin_fmaf(lemb[g*30+l], X[(768+l)*798 + nn], s);
        v = __builtin_amdgcn_exp2f(s * C2F);
      }
      lab2[idx] = v;
    }
  } else {                               // csum[r] = sum_h V[h,r]
    float* csum = (float*)(ws + WS_CSUM);
    if (tid < 12) {
      float s = 0.f;
      for (int h=0;h<798;h++) s += vw[h*12 + tid];
      csum[tid] = s;
    }
  }
}

// ---------------------------------------------------- K2: Viterbi (1 block)
__global__ __launch_bounds__(256) void viterbi_kernel(
    const float* __restrict__ start_t, const float* __restrict__ trans,
    const float* __restrict__ end_t,
    char* __restrict__ ws, float* __restrict__ out_tags)
{
  __shared__ char smem[46848];
  float* scores = (float*)smem;                    // [4][256][9] f32, 36864 B
  u64* pk = (u64*)(smem + 36864);                  // [4][256] packed funcs
  float* trl = (float*)(smem + 45056);             // [81]
  int* lastArr = (int*)(smem + 45384);             // [4]
  unsigned char* tagbuf = (unsigned char*)(smem + 45400);  // [4][256]
  const float* ner = (const float*)(ws + WS_NER);
  int* tags = (int*)(ws + WS_TAGS);
  int tid = threadIdx.x;
  int w = tid>>6, lane = tid&63;
  int b = w;
  int tt = lane < 9 ? lane : 8;
  if (tid < 81) trl[tid] = trans[tid];

  float tcol[9];
  #pragma unroll
  for (int p=0;p<9;p++) tcol[p] = trans[p*9+tt];
  const float* nb = ner + (b*256)*9 + tt;
  float score = start_t[tt] + nb[0];
  if (lane < 9) scores[(b*256 + 0)*9 + tt] = score;

  float cur[15], nxt[15];
  #pragma unroll
  for (int j=0;j<15;j++) cur[j] = nb[(1+j)*9];
  #define RL(p) (__uint_as_float(__builtin_amdgcn_readlane(__float_as_uint(score), p)) + tcol[p])
  for (int ch=0; ch<17; ch++) {
    int sb = 1 + ch*15;
    if (ch < 16) {
      #pragma unroll
      for (int j=0;j<15;j++) nxt[j] = nb[(sb+15+j)*9];
    }
    #pragma unroll
    for (int j=0;j<15;j++) {
      float m0 = fmaxf(fmaxf(RL(0),RL(1)),RL(2));
      float m1 = fmaxf(fmaxf(RL(3),RL(4)),RL(5));
      float m2 = fmaxf(fmaxf(RL(6),RL(7)),RL(8));
      score = fmaxf(fmaxf(m0,m1),m2) + cur[j];
      if (lane < 9) scores[(b*256 + sb + j)*9 + tt] = score;
    }
    #pragma unroll
    for (int j=0;j<15;j++) cur[j] = nxt[j];
  }
  {
    float fin = score + end_t[tt];
    #define RLF(p) __uint_as_float(__builtin_amdgcn_readlane(__float_as_uint(fin), p))
    float bv = RLF(0); int ba = 0;
    #pragma unroll
    for (int p=1;p<9;p++) { float v = RLF(p); if (v > bv) { bv = v; ba = p; } }
    if (lane == 0) lastArr[b] = ba;
    #undef RLF
  }
  #undef RL
  __syncthreads();

  for (int idx = tid; idx < 1024; idx += 256) {
    int bb = idx >> 8, s = idx & 255;
    u64 f;
    if (s == 255) f = 0x876543210ULL;              // identity
    else {
      const float* srow = &scores[(bb*256 + s)*9];
      float sp[9];
      #pragma unroll
      for (int p=0;p<9;p++) sp[p] = srow[p];
      f = 0;
      #pragma unroll
      for (int t=0;t<9;t++) {
        float best = sp[0] + trl[t]; int arg = 0;
        #pragma unroll
        for (int p=1;p<9;p++) {
          float v = sp[p] + trl[p*9 + t];
          if (v > best) { best = v; arg = p; }
        }
        f |= (u64)arg << (4*t);
      }
    }
    pk[bb*256 + s] = f;
  }
  __syncthreads();

  if (tid < 64) {
    int cb = tid >> 4, c = tid & 15;
    u64 fs[16];
    #pragma unroll
    for (int j=0;j<16;j++) fs[j] = pk[cb*256 + c*16 + j];
    u64 G = fs[15];
    #pragma unroll
    for (int j=14;j>=0;j--) G = fcompose(fs[j], G);
    u64 F = G;
    #pragma unroll
    for (int d=1; d<16; d<<=1) {
      u64 H = __shfl(F, tid + d);
      if (c + d < 16) F = fcompose(F, H);
    }
    int last = lastArr[cb];
    u64 Hn = __shfl(F, (c==15) ? tid : tid+1);
    unsigned t_cur = (c==15) ? (unsigned)last
                             : (unsigned)((Hn >> (4*last)) & 15u);
    #pragma unroll
    for (int j=15;j>=0;j--) {
      t_cur = (unsigned)((fs[j] >> (4*t_cur)) & 15u);
      tagbuf[cb*256 + c*16 + j] = (unsigned char)t_cur;
    }
  }
  __syncthreads();

  for (int idx = tid; idx < 1024; idx += 256) {
    int tg = (int)tagbuf[idx];
    tags[idx] = tg;
    out_tags[idx] = (float)tg;
  }
}

// ---------------------------------- K3: fuse Elab[tag] into uw2 (in place)
__global__ __launch_bounds__(256) void fuse_kernel(char* __restrict__ ws)
{
  ushort_t* uw2      = (ushort_t*)(ws + WS_UW2);
  const float* lab2  = (const float*)(ws + WS_LAB2);
  const int* tags    = (const int*)(ws + WS_TAGS);
  int idx = blockIdx.x*256 + threadIdx.x;          // < 204800 vec8 chunks
  int row = idx / 200, c8 = idx - row*200, kc = c8*8;
  int tag = tags[row];
  ushort_t* p = uw2 + (size_t)row*1600 + kc;
  i32x4 uv = *(const i32x4*)p;
  const float* lp = lab2 + tag*1600 + kc;
  f32x4 l0 = *(const f32x4*)lp;
  f32x4 l1 = *(const f32x4*)(lp+4);
  i32x4 q = (i32x4){ (int)pkbf16(hi16g(uv.x)*l0.y, lo16(uv.x)*l0.x),
                     (int)pkbf16(hi16g(uv.y)*l0.w, lo16(uv.y)*l0.z),
                     (int)pkbf16(hi16g(uv.z)*l1.y, lo16(uv.z)*l1.x),
                     (int)pkbf16(hi16g(uv.w)*l1.w, lo16(uv.w)*l1.z) };
  *(i32x4*)p = q;
}

// --------------------------------------------------------------- scorer ----
// scores = csum[r] - 2*sum_h r*V[h,r];  r = 1/(Eu*Ew+1) via bf16-domain magic.
// 1024 blocks x 512 threads, LDS sw-only 25.7KB -> 4 blk/CU = 32 waves, 1 round.
__device__ __forceinline__ unsigned rpair(int uvw, int wvw){
  f32x2 xu; xu.x = lo16(uvw); xu.y = hi16g(uvw);
  f32x2 xw; xw.x = lo16(wvw); xw.y = hi16g(wvw);
  f32x2 one2 = {1.0f, 1.0f};
  f32x2 p;
  asm("v_pk_fma_f32 %0, %1, %2, %3" : "=v"(p) : "v"(xu), "v"(xw), "v"(one2));
  unsigned pb = __builtin_amdgcn_perm(__float_as_uint(p.y), __float_as_uint(p.x), 0x07060302u);
  unsigned magic2 = 0x7EF37EF3u;
  unsigned y;
  asm("v_pk_sub_u16 %0, %1, %2" : "=v"(y) : "v"(magic2), "v"(pb));
  return y;
}

__global__ __launch_bounds__(512) void scorer_kernel(
    char* __restrict__ ws, const int* __restrict__ none_p,
    float* __restrict__ d_out)
{
  __shared__ ushort_t sw[16][804];
  const ushort_t* uw2 = (const ushort_t*)(ws + WS_UW2);
  const ushort_t* vf  = (const ushort_t*)(ws + WS_VFRAG);
  const float* csum   = (const float*)(ws + WS_CSUM);
  float* out_sc = d_out + 1024;
  int bx = blockIdx.x, tid = threadIdx.x;
  int b = bx >> 8, ti = (bx>>4)&15, tj = bx&15;
  int I0 = ti*16, J0 = tj*16, bS = b*256;

  for (int idx = tid; idx < 1600; idx += 512) {   // stage sw (already lab-fused)
    int row = idx / 100, c8 = idx - row*100, kc = c8*8;
    int grow = bS + J0 + row;
    *(i32x4*)&sw[row][kc] = *(const i32x4*)(uw2 + (size_t)grow*1600 + 800 + kc);
  }
  __syncthreads();

  int lane = tid & 63, w = tid >> 6;   // 8 waves
  int m16 = lane & 15, quad = lane >> 4;
  int none = *none_p;

  f32x4 acc[2];
  acc[0] = (f32x4){0.f,0.f,0.f,0.f};
  acc[1] = (f32x4){0.f,0.f,0.f,0.f};

  const ushort_t* su0 = uw2 + (size_t)(bS + I0 + w*2    )*1600 + quad*8;
  const ushort_t* su1 = uw2 + (size_t)(bS + I0 + w*2 + 1)*1600 + quad*8;
  const ushort_t* vlane = vf + lane*8;
  i32x4 bfc = *(const i32x4*)vlane;
  for (int c=0; c<25; c++) {
    i32x4 bfn;
    if (c < 24) bfn = *(const i32x4*)(vlane + (c+1)*512);
    int koff = c*32 + quad*8;
    i32x4 wv = *(const i32x4*)&sw[m16][koff];
    i32x4 uv0 = *(const i32x4*)(su0 + c*32);       // quad-broadcast, L1/L2
    i32x4 uv1 = *(const i32x4*)(su1 + c*32);
    bf16x8 bfrag = __builtin_bit_cast(bf16x8, bfc);
    {
      unsigned a0 = rpair(uv0.x, wv.x);
      unsigned a1 = rpair(uv0.y, wv.y);
      unsigned a2 = rpair(uv0.z, wv.z);
      unsigned a3 = rpair(uv0.w, wv.w);
      i32x4 avv = (i32x4){(int)a0,(int)a1,(int)a2,(int)a3};
      bf16x8 af = __builtin_bit_cast(bf16x8, avv);
      acc[0] = __builtin_amdgcn_mfma_f32_16x16x32_bf16(af, bfrag, acc[0], 0,0,0);
    }
    {
      unsigned a0 = rpair(uv1.x, wv.x);
      unsigned a1 = rpair(uv1.y, wv.y);
      unsigned a2 = rpair(uv1.z, wv.z);
      unsigned a3 = rpair(uv1.w, wv.w);
      i32x4 avv = (i32x4){(int)a0,(int)a1,(int)a2,(int)a3};
      bf16x8 af = __builtin_bit_cast(bf16x8, avv);
      acc[1] = __builtin_amdgcn_mfma_f32_16x16x32_bf16(af, bfrag, acc[1], 0,0,0);
    }
    bfc = bfn;
  }

  int r = m16;                         // D: col=lane&15 -> r, row=quad*4+reg -> j_local
  if (r < 12) {
    float cs = csum[r];
    #pragma unroll
    for (int it=0; it<2; it++) {
      int gi = I0 + w*2 + it;
      #pragma unroll
      for (int reg=0; reg<4; reg++) {
        int gj = J0 + quad*4 + reg;
        float v = __builtin_fmaf(-2.0f, acc[it][reg], cs);
        if (gi == gj && r == none) v = 100.0f;
        out_sc[(size_t)((bS + gi)*256 + gj)*12 + r] = v;
      }
    }
  }
}

extern "C" void kernel_launch(void* const* d_in, const int* in_sizes, int n_in,
                              void* d_out, int out_size, void* d_ws, size_t ws_size,
                              hipStream_t stream)
{
  const float* embed = (const float*)d_in[0];
  const float* lw    = (const float*)d_in[1];
  const float* lb    = (const float*)d_in[2];
  const float* st    = (const float*)d_in[3];
  const float* tr    = (const float*)d_in[4];
  const float* et    = (const float*)d_in[5];
  const float* lemb  = (const float*)d_in[6];
  const float* uw    = (const float*)d_in[7];
  const float* ub    = (const float*)d_in[8];
  const float* ww    = (const float*)d_in[9];
  const float* wb    = (const float*)d_in[10];
  const float* vw    = (const float*)d_in[11];
  const int* none_p  = (const int*)d_in[12];
  char* ws = (char*)d_ws;
  float* out = (float*)d_out;

  hipLaunchKernelGGL(gemm_prep_kernel, dim3(764), dim3(256), 0, stream,
                     embed, lw, lb, lemb, uw, ub, ww, wb, vw, ws);
  hipLaunchKernelGGL(viterbi_kernel, dim3(1), dim3(256), 0, stream,
                     st, tr, et, ws, out);
  hipLaunchKernelGGL(fuse_kernel, dim3(800), dim3(256), 0, stream, ws);
  hipLaunchKernelGGL(scorer_kernel, dim3(1024), dim3(512), 0, stream,
                     ws, none_p, out);
}